// Round 1
// baseline (789.648 us; speedup 1.0000x reference)
//
#include <hip/hip_runtime.h>
#include <hip/hip_bf16.h>

typedef __bf16 bf16;
typedef __attribute__((ext_vector_type(2))) __bf16 bf16x2;
typedef __attribute__((ext_vector_type(4))) __bf16 bf16x4;
typedef __attribute__((ext_vector_type(8))) __bf16 bf16x8;
typedef __attribute__((ext_vector_type(4))) float f32x4;

#define LDS_ASYNC16(gptr, lptr)                                                        \
  __builtin_amdgcn_global_load_lds(                                                    \
      (const __attribute__((address_space(1))) void*)(gptr),                           \
      (__attribute__((address_space(3))) void*)(lptr), 16, 0, 0)

constexpr int BATCH = 2, SEQ = 2048, DIM = 2048, NH = 16, HD = 128;
constexpr float SCALE = 0.08838834764831845f;  // 1/sqrt(128)

// ---------------------------------------------------------------- fp32 -> bf16
__global__ void cvt_f32_to_bf16(const float4* __restrict__ in,
                                bf16x4* __restrict__ out, int n4) {
  int i = blockIdx.x * blockDim.x + threadIdx.x;
  if (i >= n4) return;
  float4 v = in[i];
  bf16x4 o;
  o[0] = (bf16)v.x; o[1] = (bf16)v.y; o[2] = (bf16)v.z; o[3] = (bf16)v.w;
  out[i] = o;
}

// ---------------------------------------------- W (K,N) fp32 -> W^T (N,K) bf16
__global__ void transpose_w_bf16(const float* __restrict__ W,
                                 bf16* __restrict__ WT) {
  __shared__ float tile[32][33];
  int tx = threadIdx.x, ty = threadIdx.y;
  int bx = blockIdx.x * 32, by = blockIdx.y * 32;
#pragma unroll
  for (int j = 0; j < 32; j += 8)
    tile[ty + j][tx] = W[(size_t)(by + ty + j) * DIM + bx + tx];
  __syncthreads();
#pragma unroll
  for (int j = 0; j < 32; j += 8)
    WT[(size_t)(bx + ty + j) * DIM + by + tx] = (bf16)tile[tx][ty + j];
}

// -------------------------------------------------------------- RoPE in place
__global__ void rope_qk(bf16* __restrict__ Q, bf16* __restrict__ Kp) {
  int idx = blockIdx.x * blockDim.x + threadIdx.x;  // 0 .. B*S*DIM/2-1
  int row = idx >> 10;        // b*SEQ + s   (1024 pairs per row)
  int pr  = idx & 1023;       // h*64 + i
  int i   = pr & 63;
  int s   = row & (SEQ - 1);
  float inv = expf(-(float)i * (9.210340371976184f / 64.0f));  // 10000^(-i/64)
  float ang = (float)s * inv;
  float cs = cosf(ang), sn = sinf(ang);
  size_t base = (size_t)row * DIM + pr * 2;
  bf16x2 q = *(bf16x2*)(Q + base);
  bf16x2 k = *(bf16x2*)(Kp + base);
  float qe = (float)q[0], qo = (float)q[1];
  float ke = (float)k[0], ko = (float)k[1];
  bf16x2 qn, kn;
  qn[0] = (bf16)(qe * cs - qo * sn); qn[1] = (bf16)(qe * sn + qo * cs);
  kn[0] = (bf16)(ke * cs - ko * sn); kn[1] = (bf16)(ke * sn + ko * cs);
  *(bf16x2*)(Q + base)  = qn;
  *(bf16x2*)(Kp + base) = kn;
}

// --------------------------------------------------------------------- GEMM
// C[M,N] = A[M,K] * B[K,N], with B supplied transposed (BT[N,K]).
// MODE 0: C bf16 row-major; MODE 1: C bf16 written as V^T (B,NH,HD,SEQ);
// MODE 2: C fp32 row-major.
template <int MODE>
__global__ void gemm_bt(const bf16* __restrict__ A, const bf16* __restrict__ BT,
                        void* __restrict__ C) {
  __shared__ __attribute__((aligned(16))) bf16 As[128 * 32];
  __shared__ __attribute__((aligned(16))) bf16 Bs[128 * 32];
  const int tid = threadIdx.x;
  const int w = tid >> 6, lane = tid & 63;
  const int quad = lane >> 4, ln = lane & 15;
  const int m0 = blockIdx.y * 128, n0 = blockIdx.x * 128;
  const int wm = (w >> 1) * 64, wn = (w & 1) * 64;
  f32x4 acc[4][4] = {};

  for (int k0 = 0; k0 < DIM; k0 += 32) {
#pragma unroll
    for (int i = 0; i < 2; ++i) {
      const int c = i * 256 + tid;  // chunk id, 16B each; row = c/4, koff=(c%4)*8
      LDS_ASYNC16(A  + (size_t)(m0 + (c >> 2)) * DIM + k0 + (c & 3) * 8,
                  As + (size_t)(i * 256 + w * 64) * 8);
      LDS_ASYNC16(BT + (size_t)(n0 + (c >> 2)) * DIM + k0 + (c & 3) * 8,
                  Bs + (size_t)(i * 256 + w * 64) * 8);
    }
    __syncthreads();
    bf16x8 af[4], bfr[4];
#pragma unroll
    for (int t = 0; t < 4; ++t)
      af[t] = *(const bf16x8*)(As + (wm + t * 16 + ln) * 32 + quad * 8);
#pragma unroll
    for (int t = 0; t < 4; ++t)
      bfr[t] = *(const bf16x8*)(Bs + (wn + t * 16 + ln) * 32 + quad * 8);
#pragma unroll
    for (int mt = 0; mt < 4; ++mt)
#pragma unroll
      for (int nt = 0; nt < 4; ++nt)
        acc[mt][nt] = __builtin_amdgcn_mfma_f32_16x16x32_bf16(
            af[mt], bfr[nt], acc[mt][nt], 0, 0, 0);
    __syncthreads();
  }

  if (MODE == 0) {
    bf16* Co = (bf16*)C;
#pragma unroll
    for (int mt = 0; mt < 4; ++mt)
#pragma unroll
      for (int nt = 0; nt < 4; ++nt) {
        int gr = m0 + wm + mt * 16 + quad * 4;
        int gc = n0 + wn + nt * 16 + ln;
#pragma unroll
        for (int r = 0; r < 4; ++r)
          Co[(size_t)(gr + r) * DIM + gc] = (bf16)acc[mt][nt][r];
      }
  } else if (MODE == 1) {
    bf16* Co = (bf16*)C;  // layout (B, NH, HD, SEQ)
#pragma unroll
    for (int mt = 0; mt < 4; ++mt)
#pragma unroll
      for (int nt = 0; nt < 4; ++nt) {
        int gr = m0 + wm + mt * 16 + quad * 4;  // b*SEQ + s0 (4 consecutive s)
        int gc = n0 + wn + nt * 16 + ln;        // h*HD + d
        int b = gr >> 11, s0 = gr & (SEQ - 1);
        int h = gc >> 7, d = gc & (HD - 1);
        bf16x4 pk;
#pragma unroll
        for (int r = 0; r < 4; ++r) pk[r] = (bf16)acc[mt][nt][r];
        *(bf16x4*)(Co + ((size_t)((b * NH + h) * HD + d)) * SEQ + s0) = pk;
      }
  } else {
    float* Co = (float*)C;
#pragma unroll
    for (int mt = 0; mt < 4; ++mt)
#pragma unroll
      for (int nt = 0; nt < 4; ++nt) {
        int gr = m0 + wm + mt * 16 + quad * 4;
        int gc = n0 + wn + nt * 16 + ln;
#pragma unroll
        for (int r = 0; r < 4; ++r)
          Co[(size_t)(gr + r) * DIM + gc] = acc[mt][nt][r];
      }
  }
}

// -------------------------------------------------------------- flash attn
// Q,K: (B,SEQ,NH*HD) bf16 row-major (RoPE'd). VT: (B,NH,HD,SEQ) bf16.
// O: (B,SEQ,NH*HD) bf16. One block = (b,h,128-row q-tile), 4 waves x 32 rows.
__global__ void flash_attn(const bf16* __restrict__ Q, const bf16* __restrict__ K,
                           const bf16* __restrict__ VT, bf16* __restrict__ O) {
  __shared__ __attribute__((aligned(16))) bf16 Ks[64 * 128];   // [kc][hd]
  __shared__ __attribute__((aligned(16))) bf16 VTs[128 * 64];  // [d][kc]
  __shared__ __attribute__((aligned(16))) bf16 Ps[4][32 * 64]; // per-wave [qr][kc]
  const int tid = threadIdx.x;
  const int w = tid >> 6, lane = tid & 63, quad = lane >> 4, ln = lane & 15;
  const int q0 = blockIdx.x * 128;
  const int b = blockIdx.y >> 4, h = blockIdx.y & 15;

  bf16x8 qf[2][4];  // A-operand frags: [m-tile][k-chunk]
#pragma unroll
  for (int mt = 0; mt < 2; ++mt)
#pragma unroll
    for (int kc = 0; kc < 4; ++kc)
      qf[mt][kc] = *(const bf16x8*)(Q + ((size_t)b * SEQ + q0 + w * 32 + mt * 16 + ln) * DIM +
                                    h * HD + kc * 32 + quad * 8);
  f32x4 o[2][8] = {};
  float mst[2][4], lst[2][4];
#pragma unroll
  for (int mt = 0; mt < 2; ++mt)
#pragma unroll
    for (int r = 0; r < 4; ++r) { mst[mt][r] = -1e30f; lst[mt][r] = 0.f; }

  const int nkt = (q0 + 128) >> 6;  // causal: k-tiles of 64 up to diagonal
  for (int kt = 0; kt < nkt; ++kt) {
    __syncthreads();  // prev-iter LDS reads done before restaging
#pragma unroll
    for (int i = 0; i < 4; ++i) {
      const int c = i * 256 + tid;  // 1024 16B chunks per tile
      LDS_ASYNC16(K + ((size_t)b * SEQ + kt * 64 + (c >> 4)) * DIM + h * HD + (c & 15) * 8,
                  Ks + (size_t)(i * 256 + w * 64) * 8);
      LDS_ASYNC16(VT + ((size_t)((b * NH + h) * HD) + (c >> 3)) * SEQ + kt * 64 + (c & 7) * 8,
                  VTs + (size_t)(i * 256 + w * 64) * 8);
    }
    __syncthreads();

    // S = Q K^T (scaled later); C-layout: col(ln)=k-col, row(quad*4+r)=q-row
    f32x4 s[2][4] = {};
#pragma unroll
    for (int nt = 0; nt < 4; ++nt) {
      bf16x8 kf[4];
#pragma unroll
      for (int kc = 0; kc < 4; ++kc)
        kf[kc] = *(const bf16x8*)(Ks + (nt * 16 + ln) * 128 + kc * 32 + quad * 8);
#pragma unroll
      for (int kc = 0; kc < 4; ++kc)
#pragma unroll
        for (int mt = 0; mt < 2; ++mt)
          s[mt][nt] = __builtin_amdgcn_mfma_f32_16x16x32_bf16(
              qf[mt][kc], kf[kc], s[mt][nt], 0, 0, 0);
    }

    const bool diag = (kt * 64 + 63 > q0);
#pragma unroll
    for (int mt = 0; mt < 2; ++mt)
#pragma unroll
      for (int nt = 0; nt < 4; ++nt)
#pragma unroll
        for (int r = 0; r < 4; ++r) {
          float v = s[mt][nt][r] * SCALE;
          if (diag) {
            int kg = kt * 64 + nt * 16 + ln;
            int qg = q0 + w * 32 + mt * 16 + quad * 4 + r;
            if (kg > qg) v = -1e30f;
          }
          s[mt][nt][r] = v;
        }

    // online softmax per q-row; row lives in 16-lane group (fixed quad)
#pragma unroll
    for (int mt = 0; mt < 2; ++mt)
#pragma unroll
      for (int r = 0; r < 4; ++r) {
        float rm = s[mt][0][r];
#pragma unroll
        for (int nt = 1; nt < 4; ++nt) rm = fmaxf(rm, s[mt][nt][r]);
        rm = fmaxf(rm, __shfl_xor(rm, 1));
        rm = fmaxf(rm, __shfl_xor(rm, 2));
        rm = fmaxf(rm, __shfl_xor(rm, 4));
        rm = fmaxf(rm, __shfl_xor(rm, 8));
        float mold = mst[mt][r];
        float mnew = fmaxf(mold, rm);
        float alpha = __expf(mold - mnew);
        mst[mt][r] = mnew;
        float rs = 0.f;
#pragma unroll
        for (int nt = 0; nt < 4; ++nt) {
          float p = __expf(s[mt][nt][r] - mnew);
          rs += p;
          Ps[w][(mt * 16 + quad * 4 + r) * 64 + nt * 16 + ln] = (bf16)p;
        }
        lst[mt][r] = lst[mt][r] * alpha + rs;  // lane-partial; reduced at end
#pragma unroll
        for (int nd = 0; nd < 8; ++nd) o[mt][nd][r] *= alpha;
      }
    __syncthreads();  // P visible (and lgkm drained) before A-frag reads

    // O += P V : A = P (from per-wave LDS), B = V (from VTs, n=d)
#pragma unroll
    for (int kc2 = 0; kc2 < 2; ++kc2) {
      bf16x8 pf[2];
#pragma unroll
      for (int mt = 0; mt < 2; ++mt)
        pf[mt] = *(const bf16x8*)(&Ps[w][(mt * 16 + ln) * 64 + kc2 * 32 + quad * 8]);
#pragma unroll
      for (int nd = 0; nd < 8; ++nd) {
        bf16x8 vf = *(const bf16x8*)(VTs + (nd * 16 + ln) * 64 + kc2 * 32 + quad * 8);
#pragma unroll
        for (int mt = 0; mt < 2; ++mt)
          o[mt][nd] = __builtin_amdgcn_mfma_f32_16x16x32_bf16(
              pf[mt], vf, o[mt][nd], 0, 0, 0);
      }
    }
  }

  // normalize (reduce lane-partial l across the 16-lane row group) and store
#pragma unroll
  for (int mt = 0; mt < 2; ++mt)
#pragma unroll
    for (int r = 0; r < 4; ++r) {
      float l = lst[mt][r];
      l += __shfl_xor(l, 1);
      l += __shfl_xor(l, 2);
      l += __shfl_xor(l, 4);
      l += __shfl_xor(l, 8);
      float inv = 1.f / l;
      int qg = q0 + w * 32 + mt * 16 + quad * 4 + r;
#pragma unroll
      for (int nd = 0; nd < 8; ++nd)
        O[((size_t)b * SEQ + qg) * DIM + h * HD + nd * 16 + ln] =
            (bf16)(o[mt][nd][r] * inv);
    }
}

// ------------------------------------------------------------------- launch
extern "C" void kernel_launch(void* const* d_in, const int* in_sizes, int n_in,
                              void* d_out, int out_size, void* d_ws, size_t ws_size,
                              hipStream_t stream) {
  (void)in_sizes; (void)n_in; (void)out_size; (void)ws_size;
  const float* x  = (const float*)d_in[0];
  const float* Wq = (const float*)d_in[1];
  const float* Wk = (const float*)d_in[2];
  const float* Wv = (const float*)d_in[3];
  const float* Wo = (const float*)d_in[4];

  char* ws = (char*)d_ws;
  const size_t WB = (size_t)DIM * DIM * 2;          // 8 MB per transposed weight
  const size_t XB = (size_t)BATCH * SEQ * DIM * 2;  // 16 MB per activation
  bf16* WqT = (bf16*)(ws);
  bf16* WkT = (bf16*)(ws + WB);
  bf16* WvT = (bf16*)(ws + 2 * WB);
  bf16* WoT = (bf16*)(ws + 3 * WB);
  bf16* xb  = (bf16*)(ws + 4 * WB);
  bf16* Qb  = (bf16*)(ws + 4 * WB + XB);
  bf16* Kb  = (bf16*)(ws + 4 * WB + 2 * XB);
  bf16* VT  = (bf16*)(ws + 4 * WB + 3 * XB);
  bf16* Ab  = xb;  // attn output aliases xb (xb dead after V GEMM)

  int n4 = BATCH * SEQ * DIM / 4;
  cvt_f32_to_bf16<<<n4 / 256, 256, 0, stream>>>((const float4*)x, (bf16x4*)xb, n4);
  dim3 tb(32, 8), tg(DIM / 32, DIM / 32);
  transpose_w_bf16<<<tg, tb, 0, stream>>>(Wq, WqT);
  transpose_w_bf16<<<tg, tb, 0, stream>>>(Wk, WkT);
  transpose_w_bf16<<<tg, tb, 0, stream>>>(Wv, WvT);
  transpose_w_bf16<<<tg, tb, 0, stream>>>(Wo, WoT);

  dim3 gg(DIM / 128, BATCH * SEQ / 128);
  gemm_bt<0><<<gg, 256, 0, stream>>>(xb, WqT, Qb);
  gemm_bt<0><<<gg, 256, 0, stream>>>(xb, WkT, Kb);
  gemm_bt<1><<<gg, 256, 0, stream>>>(xb, WvT, VT);

  int npair = BATCH * SEQ * DIM / 2;
  rope_qk<<<npair / 256, 256, 0, stream>>>(Qb, Kb);

  dim3 fg(SEQ / 128, BATCH * NH);
  flash_attn<<<fg, 256, 0, stream>>>(Qb, Kb, VT, Ab);

  gemm_bt<2><<<gg, 256, 0, stream>>>(Ab, WoT, d_out);
}

// Round 2
// 554.202 us; speedup vs baseline: 1.4248x; 1.4248x over previous
//
#include <hip/hip_runtime.h>
#include <hip/hip_bf16.h>

typedef __bf16 bf16;
typedef __attribute__((ext_vector_type(2))) __bf16 bf16x2;
typedef __attribute__((ext_vector_type(4))) __bf16 bf16x4;
typedef __attribute__((ext_vector_type(8))) __bf16 bf16x8;
typedef __attribute__((ext_vector_type(4))) float f32x4;

#define LDS_ASYNC16(gptr, lptr)                                                        \
  __builtin_amdgcn_global_load_lds(                                                    \
      (const __attribute__((address_space(1))) void*)(gptr),                           \
      (__attribute__((address_space(3))) void*)(lptr), 16, 0, 0)

constexpr int BATCH = 2, SEQ = 2048, DIM = 2048, NH = 16, HD = 128;
constexpr float SCALE = 0.08838834764831845f;  // 1/sqrt(128)

// ---------------------------------------------------------------- fp32 -> bf16
__global__ void cvt_f32_to_bf16(const float4* __restrict__ in,
                                bf16x4* __restrict__ out, int n4) {
  int i = blockIdx.x * blockDim.x + threadIdx.x;
  if (i >= n4) return;
  float4 v = in[i];
  bf16x4 o;
  o[0] = (bf16)v.x; o[1] = (bf16)v.y; o[2] = (bf16)v.z; o[3] = (bf16)v.w;
  out[i] = o;
}

// ---------------------------------------------- W (K,N) fp32 -> W^T (N,K) bf16
__global__ void transpose_w_bf16(const float* __restrict__ W,
                                 bf16* __restrict__ WT) {
  __shared__ float tile[32][33];
  int tx = threadIdx.x, ty = threadIdx.y;
  int bx = blockIdx.x * 32, by = blockIdx.y * 32;
#pragma unroll
  for (int j = 0; j < 32; j += 8)
    tile[ty + j][tx] = W[(size_t)(by + ty + j) * DIM + bx + tx];
  __syncthreads();
#pragma unroll
  for (int j = 0; j < 32; j += 8)
    WT[(size_t)(bx + ty + j) * DIM + by + tx] = (bf16)tile[tx][ty + j];
}

// -------------------------------------------------------------- RoPE in place
__global__ void rope_qk(bf16* __restrict__ Q, bf16* __restrict__ Kp) {
  int idx = blockIdx.x * blockDim.x + threadIdx.x;  // 0 .. B*S*DIM/2-1
  int row = idx >> 10;        // b*SEQ + s   (1024 pairs per row)
  int pr  = idx & 1023;       // h*64 + i
  int i   = pr & 63;
  int s   = row & (SEQ - 1);
  float inv = expf(-(float)i * (9.210340371976184f / 64.0f));  // 10000^(-i/64)
  float ang = (float)s * inv;
  float cs = cosf(ang), sn = sinf(ang);
  size_t base = (size_t)row * DIM + pr * 2;
  bf16x2 q = *(bf16x2*)(Q + base);
  bf16x2 k = *(bf16x2*)(Kp + base);
  float qe = (float)q[0], qo = (float)q[1];
  float ke = (float)k[0], ko = (float)k[1];
  bf16x2 qn, kn;
  qn[0] = (bf16)(qe * cs - qo * sn); qn[1] = (bf16)(qe * sn + qo * cs);
  kn[0] = (bf16)(ke * cs - ko * sn); kn[1] = (bf16)(ke * sn + ko * cs);
  *(bf16x2*)(Q + base)  = qn;
  *(bf16x2*)(Kp + base) = kn;
}

// --------------------------------------------------------------------- GEMM
// C[M,N] = A[M,K] * B[K,N], with B supplied transposed (BT[N,K]).
// MODE 0: C bf16 row-major; MODE 1: C bf16 written as V^T (B,NH,HD,SEQ);
// MODE 2: C fp32 row-major.
template <int MODE>
__global__ __launch_bounds__(256) void gemm_bt(const bf16* __restrict__ A,
                                               const bf16* __restrict__ BT,
                                               void* __restrict__ C) {
  __shared__ __attribute__((aligned(16))) bf16 As[128 * 32];
  __shared__ __attribute__((aligned(16))) bf16 Bs[128 * 32];
  const int tid = threadIdx.x;
  const int w = tid >> 6, lane = tid & 63;
  const int quad = lane >> 4, ln = lane & 15;
  const int m0 = blockIdx.y * 128, n0 = blockIdx.x * 128;
  const int wm = (w >> 1) * 64, wn = (w & 1) * 64;
  f32x4 acc[4][4] = {};

  for (int k0 = 0; k0 < DIM; k0 += 32) {
#pragma unroll
    for (int i = 0; i < 2; ++i) {
      const int c = i * 256 + tid;  // chunk id, 16B each; row = c/4, koff=(c%4)*8
      LDS_ASYNC16(A  + (size_t)(m0 + (c >> 2)) * DIM + k0 + (c & 3) * 8,
                  As + (size_t)(i * 256 + w * 64) * 8);
      LDS_ASYNC16(BT + (size_t)(n0 + (c >> 2)) * DIM + k0 + (c & 3) * 8,
                  Bs + (size_t)(i * 256 + w * 64) * 8);
    }
    __syncthreads();
    bf16x8 af[4], bfr[4];
#pragma unroll
    for (int t = 0; t < 4; ++t)
      af[t] = *(const bf16x8*)(As + (wm + t * 16 + ln) * 32 + quad * 8);
#pragma unroll
    for (int t = 0; t < 4; ++t)
      bfr[t] = *(const bf16x8*)(Bs + (wn + t * 16 + ln) * 32 + quad * 8);
#pragma unroll
    for (int mt = 0; mt < 4; ++mt)
#pragma unroll
      for (int nt = 0; nt < 4; ++nt)
        acc[mt][nt] = __builtin_amdgcn_mfma_f32_16x16x32_bf16(
            af[mt], bfr[nt], acc[mt][nt], 0, 0, 0);
    __syncthreads();
  }

  if (MODE == 0) {
    bf16* Co = (bf16*)C;
#pragma unroll
    for (int mt = 0; mt < 4; ++mt)
#pragma unroll
      for (int nt = 0; nt < 4; ++nt) {
        int gr = m0 + wm + mt * 16 + quad * 4;
        int gc = n0 + wn + nt * 16 + ln;
#pragma unroll
        for (int r = 0; r < 4; ++r)
          Co[(size_t)(gr + r) * DIM + gc] = (bf16)acc[mt][nt][r];
      }
  } else if (MODE == 1) {
    bf16* Co = (bf16*)C;  // layout (B, NH, HD, SEQ)
#pragma unroll
    for (int mt = 0; mt < 4; ++mt)
#pragma unroll
      for (int nt = 0; nt < 4; ++nt) {
        int gr = m0 + wm + mt * 16 + quad * 4;  // b*SEQ + s0 (4 consecutive s)
        int gc = n0 + wn + nt * 16 + ln;        // h*HD + d
        int b = gr >> 11, s0 = gr & (SEQ - 1);
        int h = gc >> 7, d = gc & (HD - 1);
        bf16x4 pk;
#pragma unroll
        for (int r = 0; r < 4; ++r) pk[r] = (bf16)acc[mt][nt][r];
        *(bf16x4*)(Co + ((size_t)((b * NH + h) * HD + d)) * SEQ + s0) = pk;
      }
  } else {
    float* Co = (float*)C;
#pragma unroll
    for (int mt = 0; mt < 4; ++mt)
#pragma unroll
      for (int nt = 0; nt < 4; ++nt) {
        int gr = m0 + wm + mt * 16 + quad * 4;
        int gc = n0 + wn + nt * 16 + ln;
#pragma unroll
        for (int r = 0; r < 4; ++r)
          Co[(size_t)(gr + r) * DIM + gc] = acc[mt][nt][r];
      }
  }
}

// -------------------------------------------------------------- flash attn
// Q,K: (B,SEQ,NH*HD) bf16 row-major (RoPE'd). VT: (B,NH,HD,SEQ) bf16.
// O: (B,SEQ,NH*HD) bf16. One block = (b,h,128-row q-tile), 4 waves x 32 rows.
// LDS layouts are XOR-chunk-swizzled (16B chunks) so b128 fragment reads are
// <=2-way bank aliased (free); global_load_lds staging picks the permuted
// source chunk since the LDS dest is forced lane-contiguous.
constexpr int PSTR = 72;  // Ps row stride (+8 el pad): 144B = 36 words, 16B-aligned
__global__ __launch_bounds__(256) void flash_attn(const bf16* __restrict__ Q,
                                                  const bf16* __restrict__ K,
                                                  const bf16* __restrict__ VT,
                                                  bf16* __restrict__ O) {
  __shared__ __attribute__((aligned(16))) bf16 Ks[64 * 128];    // [kc][16 chunks swz]
  __shared__ __attribute__((aligned(16))) bf16 VTs[128 * 64];   // [d][8 chunks swz]
  __shared__ __attribute__((aligned(16))) bf16 Ps[4][32 * PSTR];// per-wave [qr][kc]
  const int tid = threadIdx.x;
  const int w = tid >> 6, lane = tid & 63, quad = lane >> 4, ln = lane & 15;
  const int q0 = (gridDim.x - 1 - blockIdx.x) * 128;  // long blocks first
  const int b = blockIdx.y >> 4, h = blockIdx.y & 15;

  bf16x8 qf[2][4];  // A-operand frags: [m-tile][k-chunk]
#pragma unroll
  for (int mt = 0; mt < 2; ++mt)
#pragma unroll
    for (int kc = 0; kc < 4; ++kc)
      qf[mt][kc] = *(const bf16x8*)(Q + ((size_t)b * SEQ + q0 + w * 32 + mt * 16 + ln) * DIM +
                                    h * HD + kc * 32 + quad * 8);
  f32x4 o[2][8] = {};
  float mst[2][4], lst[2][4];
#pragma unroll
  for (int mt = 0; mt < 2; ++mt)
#pragma unroll
    for (int r = 0; r < 4; ++r) { mst[mt][r] = -1e30f; lst[mt][r] = 0.f; }

  const int nkt = (q0 + 128) >> 6;  // causal: k-tiles of 64 up to diagonal
  for (int kt = 0; kt < nkt; ++kt) {
    __syncthreads();  // prev-iter LDS reads done before restaging
#pragma unroll
    for (int i = 0; i < 4; ++i) {
      const int c = i * 256 + tid;  // 1024 16B chunks per tile
      // K: slot c = row(c>>4) * 16 + physchunk(c&15); fetch logical chunk = phys ^ (row&15)
      LDS_ASYNC16(K + ((size_t)b * SEQ + kt * 64 + (c >> 4)) * DIM + h * HD +
                      (((c & 15) ^ ((c >> 4) & 15)) * 8),
                  Ks + (size_t)(i * 256 + w * 64) * 8);
      // VT: slot c = row(c>>3) * 8 + physchunk(c&7); fetch logical chunk = phys ^ (row&7)
      LDS_ASYNC16(VT + ((size_t)((b * NH + h) * HD) + (c >> 3)) * SEQ + kt * 64 +
                      (((c & 7) ^ ((c >> 3) & 7)) * 8),
                  VTs + (size_t)(i * 256 + w * 64) * 8);
    }
    __syncthreads();

    // S = Q K^T (scaled later); C-layout: col(ln)=k-col, row(quad*4+r)=q-row
    f32x4 s[2][4] = {};
#pragma unroll
    for (int nt = 0; nt < 4; ++nt) {
      bf16x8 kf[4];
#pragma unroll
      for (int kc = 0; kc < 4; ++kc)
        kf[kc] = *(const bf16x8*)(Ks + (nt * 16 + ln) * 128 +
                                  (((kc * 4 + quad) ^ ln) * 8));
#pragma unroll
      for (int kc = 0; kc < 4; ++kc)
#pragma unroll
        for (int mt = 0; mt < 2; ++mt)
          s[mt][nt] = __builtin_amdgcn_mfma_f32_16x16x32_bf16(
              qf[mt][kc], kf[kc], s[mt][nt], 0, 0, 0);
    }

    const bool diag = (kt * 64 + 63 > q0);
#pragma unroll
    for (int mt = 0; mt < 2; ++mt)
#pragma unroll
      for (int nt = 0; nt < 4; ++nt)
#pragma unroll
        for (int r = 0; r < 4; ++r) {
          float v = s[mt][nt][r] * SCALE;
          if (diag) {
            int kg = kt * 64 + nt * 16 + ln;
            int qg = q0 + w * 32 + mt * 16 + quad * 4 + r;
            if (kg > qg) v = -1e30f;
          }
          s[mt][nt][r] = v;
        }

    // online softmax per q-row; row lives in 16-lane group (fixed quad)
#pragma unroll
    for (int mt = 0; mt < 2; ++mt)
#pragma unroll
      for (int r = 0; r < 4; ++r) {
        float rm = s[mt][0][r];
#pragma unroll
        for (int nt = 1; nt < 4; ++nt) rm = fmaxf(rm, s[mt][nt][r]);
        rm = fmaxf(rm, __shfl_xor(rm, 1));
        rm = fmaxf(rm, __shfl_xor(rm, 2));
        rm = fmaxf(rm, __shfl_xor(rm, 4));
        rm = fmaxf(rm, __shfl_xor(rm, 8));
        float mold = mst[mt][r];
        float mnew = fmaxf(mold, rm);
        float alpha = __expf(mold - mnew);
        mst[mt][r] = mnew;
        float rs = 0.f;
#pragma unroll
        for (int nt = 0; nt < 4; ++nt) {
          float p = __expf(s[mt][nt][r] - mnew);
          rs += p;
          Ps[w][(mt * 16 + quad * 4 + r) * PSTR + nt * 16 + ln] = (bf16)p;
        }
        lst[mt][r] = lst[mt][r] * alpha + rs;  // lane-partial; reduced at end
#pragma unroll
        for (int nd = 0; nd < 8; ++nd) o[mt][nd][r] *= alpha;
      }
    __syncthreads();  // P visible (and lgkm drained) before A-frag reads

    // O += P V : A = P (from per-wave LDS), B = V (from VTs, n=d)
#pragma unroll
    for (int kc2 = 0; kc2 < 2; ++kc2) {
      bf16x8 pf[2];
#pragma unroll
      for (int mt = 0; mt < 2; ++mt)
        pf[mt] = *(const bf16x8*)(&Ps[w][(mt * 16 + ln) * PSTR + kc2 * 32 + quad * 8]);
#pragma unroll
      for (int nd = 0; nd < 8; ++nd) {
        bf16x8 vf = *(const bf16x8*)(VTs + (nd * 16 + ln) * 64 +
                                     (((kc2 * 4 + quad) ^ (ln & 7)) * 8));
#pragma unroll
        for (int mt = 0; mt < 2; ++mt)
          o[mt][nd] = __builtin_amdgcn_mfma_f32_16x16x32_bf16(
              pf[mt], vf, o[mt][nd], 0, 0, 0);
      }
    }
  }

  // normalize (reduce lane-partial l across the 16-lane row group) and store
#pragma unroll
  for (int mt = 0; mt < 2; ++mt)
#pragma unroll
    for (int r = 0; r < 4; ++r) {
      float l = lst[mt][r];
      l += __shfl_xor(l, 1);
      l += __shfl_xor(l, 2);
      l += __shfl_xor(l, 4);
      l += __shfl_xor(l, 8);
      float inv = 1.f / l;
      int qg = q0 + w * 32 + mt * 16 + quad * 4 + r;
#pragma unroll
      for (int nd = 0; nd < 8; ++nd)
        O[((size_t)b * SEQ + qg) * DIM + h * HD + nd * 16 + ln] =
            (bf16)(o[mt][nd][r] * inv);
    }
}

// ------------------------------------------------------------------- launch
extern "C" void kernel_launch(void* const* d_in, const int* in_sizes, int n_in,
                              void* d_out, int out_size, void* d_ws, size_t ws_size,
                              hipStream_t stream) {
  (void)in_sizes; (void)n_in; (void)out_size; (void)ws_size;
  const float* x  = (const float*)d_in[0];
  const float* Wq = (const float*)d_in[1];
  const float* Wk = (const float*)d_in[2];
  const float* Wv = (const float*)d_in[3];
  const float* Wo = (const float*)d_in[4];

  char* ws = (char*)d_ws;
  const size_t WB = (size_t)DIM * DIM * 2;          // 8 MB per transposed weight
  const size_t XB = (size_t)BATCH * SEQ * DIM * 2;  // 16 MB per activation
  bf16* WqT = (bf16*)(ws);
  bf16* WkT = (bf16*)(ws + WB);
  bf16* WvT = (bf16*)(ws + 2 * WB);
  bf16* WoT = (bf16*)(ws + 3 * WB);
  bf16* xb  = (bf16*)(ws + 4 * WB);
  bf16* Qb  = (bf16*)(ws + 4 * WB + XB);
  bf16* Kb  = (bf16*)(ws + 4 * WB + 2 * XB);
  bf16* VT  = (bf16*)(ws + 4 * WB + 3 * XB);
  bf16* Ab  = xb;  // attn output aliases xb (xb dead after V GEMM)

  int n4 = BATCH * SEQ * DIM / 4;
  cvt_f32_to_bf16<<<n4 / 256, 256, 0, stream>>>((const float4*)x, (bf16x4*)xb, n4);
  dim3 tb(32, 8), tg(DIM / 32, DIM / 32);
  transpose_w_bf16<<<tg, tb, 0, stream>>>(Wq, WqT);
  transpose_w_bf16<<<tg, tb, 0, stream>>>(Wk, WkT);
  transpose_w_bf16<<<tg, tb, 0, stream>>>(Wv, WvT);
  transpose_w_bf16<<<tg, tb, 0, stream>>>(Wo, WoT);

  dim3 gg(DIM / 128, BATCH * SEQ / 128);
  gemm_bt<0><<<gg, 256, 0, stream>>>(xb, WqT, Qb);
  gemm_bt<0><<<gg, 256, 0, stream>>>(xb, WkT, Kb);
  gemm_bt<1><<<gg, 256, 0, stream>>>(xb, WvT, VT);

  int npair = BATCH * SEQ * DIM / 2;
  rope_qk<<<npair / 256, 256, 0, stream>>>(Qb, Kb);

  dim3 fg(SEQ / 128, BATCH * NH);
  flash_attn<<<fg, 256, 0, stream>>>(Qb, Kb, VT, Ab);

  gemm_bt<2><<<gg, 256, 0, stream>>>(Ab, WoT, d_out);
}

// Round 3
// 480.195 us; speedup vs baseline: 1.6444x; 1.1541x over previous
//
#include <hip/hip_runtime.h>
#include <hip/hip_bf16.h>
#include <math.h>

typedef __bf16 bf16;
typedef __attribute__((ext_vector_type(2))) __bf16 bf16x2;
typedef __attribute__((ext_vector_type(4))) __bf16 bf16x4;
typedef __attribute__((ext_vector_type(8))) __bf16 bf16x8;
typedef __attribute__((ext_vector_type(4))) float f32x4;

#define LDS_ASYNC16(gptr, lptr)                                                        \
  __builtin_amdgcn_global_load_lds(                                                    \
      (const __attribute__((address_space(1))) void*)(gptr),                           \
      (__attribute__((address_space(3))) void*)(lptr), 16, 0, 0)

constexpr int BATCH = 2, SEQ = 2048, DIM = 2048, NH = 16, HD = 128;
// 1/sqrt(128) * log2(e): folded into Q at projection; flash works in exp2 domain
constexpr float QSC = 0.12751744f;
constexpr float FREQC = 0.20762050593046f;  // log2(10000)/64

// ---- DPP 16-lane reductions (row_ror rotates within 16-lane rows on gfx9) ----
template <int CTRL>
__device__ __forceinline__ float dpp_mov_f(float x) {
  return __int_as_float(__builtin_amdgcn_update_dpp(
      __float_as_int(x), __float_as_int(x), CTRL, 0xf, 0xf, false));
}
__device__ __forceinline__ float rowmax16(float x) {
  x = fmaxf(x, dpp_mov_f<0x121>(x));  // ror:1
  x = fmaxf(x, dpp_mov_f<0x122>(x));  // ror:2
  x = fmaxf(x, dpp_mov_f<0x124>(x));  // ror:4
  x = fmaxf(x, dpp_mov_f<0x128>(x));  // ror:8
  return x;
}
__device__ __forceinline__ float rowsum16(float x) {
  x += dpp_mov_f<0x121>(x);
  x += dpp_mov_f<0x122>(x);
  x += dpp_mov_f<0x124>(x);
  x += dpp_mov_f<0x128>(x);
  return x;
}

// ---------------------------------------------------------------- fp32 -> bf16
__global__ void cvt_f32_to_bf16(const float4* __restrict__ in,
                                bf16x4* __restrict__ out, int n4) {
  int i = blockIdx.x * blockDim.x + threadIdx.x;
  if (i >= n4) return;
  float4 v = in[i];
  bf16x4 o;
  o[0] = (bf16)v.x; o[1] = (bf16)v.y; o[2] = (bf16)v.z; o[3] = (bf16)v.w;
  out[i] = o;
}

// ---------------------------------------------- W (K,N) fp32 -> W^T (N,K) bf16
__global__ void transpose_w_bf16(const float* __restrict__ W,
                                 bf16* __restrict__ WT) {
  __shared__ float tile[32][33];
  int tx = threadIdx.x, ty = threadIdx.y;
  int bx = blockIdx.x * 32, by = blockIdx.y * 32;
#pragma unroll
  for (int j = 0; j < 32; j += 8)
    tile[ty + j][tx] = W[(size_t)(by + ty + j) * DIM + bx + tx];
  __syncthreads();
#pragma unroll
  for (int j = 0; j < 32; j += 8)
    WT[(size_t)(bx + ty + j) * DIM + by + tx] = (bf16)tile[tx][ty + j];
}

// ----------------------------------------------------- fused QKV GEMM + RoPE
// A[4096,2048] bf16, BT = [WqT;WkT;WvT] (6144,2048) bf16.
// n0<2048: Q (rope, *QSC, row-major); <4096: K (rope, row-major);
// else: V written as V^T (B,NH,HD,SEQ).
__global__ __launch_bounds__(256) void gemm_qkv(const bf16* __restrict__ A,
                                                const bf16* __restrict__ BT,
                                                bf16* __restrict__ Qb,
                                                bf16* __restrict__ Kb,
                                                bf16* __restrict__ VTo) {
  __shared__ __attribute__((aligned(16))) bf16 As[128 * 32];
  __shared__ __attribute__((aligned(16))) bf16 Bs[128 * 32];
  const int tid = threadIdx.x;
  const int w = tid >> 6, lane = tid & 63;
  const int quad = lane >> 4, ln = lane & 15;
  const int m0 = blockIdx.y * 128, n0 = blockIdx.x * 128;
  const int wm = (w >> 1) * 64, wn = (w & 1) * 64;
  f32x4 acc[4][4] = {};

  for (int k0 = 0; k0 < DIM; k0 += 32) {
#pragma unroll
    for (int i = 0; i < 2; ++i) {
      const int c = i * 256 + tid;
      LDS_ASYNC16(A  + (size_t)(m0 + (c >> 2)) * DIM + k0 + (c & 3) * 8,
                  As + (size_t)(i * 256 + w * 64) * 8);
      LDS_ASYNC16(BT + (size_t)(n0 + (c >> 2)) * DIM + k0 + (c & 3) * 8,
                  Bs + (size_t)(i * 256 + w * 64) * 8);
    }
    __syncthreads();
    bf16x8 af[4], bfr[4];
#pragma unroll
    for (int t = 0; t < 4; ++t)
      af[t] = *(const bf16x8*)(As + (wm + t * 16 + ln) * 32 + quad * 8);
#pragma unroll
    for (int t = 0; t < 4; ++t)
      bfr[t] = *(const bf16x8*)(Bs + (wn + t * 16 + ln) * 32 + quad * 8);
#pragma unroll
    for (int mt = 0; mt < 4; ++mt)
#pragma unroll
      for (int nt = 0; nt < 4; ++nt)
        acc[mt][nt] = __builtin_amdgcn_mfma_f32_16x16x32_bf16(
            af[mt], bfr[nt], acc[mt][nt], 0, 0, 0);
    __syncthreads();
  }

  const int sel = n0 >> 11;  // 0:Q 1:K 2:V  (block-uniform)
  if (sel == 2) {
#pragma unroll
    for (int mt = 0; mt < 4; ++mt)
#pragma unroll
      for (int nt = 0; nt < 4; ++nt) {
        int gr = m0 + wm + mt * 16 + quad * 4;
        int fc = (n0 + wn + nt * 16 + ln) & 2047;
        int b = gr >> 11, s0 = gr & (SEQ - 1);
        int h = fc >> 7, d = fc & (HD - 1);
        bf16x4 pk;
#pragma unroll
        for (int r = 0; r < 4; ++r) pk[r] = (bf16)acc[mt][nt][r];
        *(bf16x4*)(VTo + ((size_t)((b * NH + h) * HD + d)) * SEQ + s0) = pk;
      }
  } else {
    bf16* Dst = sel ? Kb : Qb;
    const float osc = sel ? 1.0f : QSC;
#pragma unroll
    for (int nt = 0; nt < 4; ++nt) {
      int gc = n0 + wn + nt * 16 + ln;
      int fc = gc & 2047, d = fc & (HD - 1);
      float freq = exp2f(-(float)(d >> 1) * FREQC);
      bool ev = !(d & 1);
#pragma unroll
      for (int mt = 0; mt < 4; ++mt) {
#pragma unroll
        for (int r = 0; r < 4; ++r) {
          int gr = m0 + wm + mt * 16 + quad * 4 + r;
          int s = gr & (SEQ - 1);
          float ang = (float)s * freq;
          float sn, cs;
          __sincosf(ang, &sn, &cs);
          float own = acc[mt][nt][r];
          float oth = __shfl_xor(own, 1);  // partner feature (d^1), lane ln^1
          float res = ev ? (own * cs - oth * sn) : (oth * sn + own * cs);
          Dst[(size_t)gr * DIM + fc] = (bf16)(res * osc);
        }
      }
    }
  }
}

// --------------------------------------------------------------------- GEMM
// C[M,N] = A * BT^T; MODE 2: C fp32 row-major (used for the Wo projection).
template <int MODE>
__global__ __launch_bounds__(256) void gemm_bt(const bf16* __restrict__ A,
                                               const bf16* __restrict__ BT,
                                               void* __restrict__ C) {
  __shared__ __attribute__((aligned(16))) bf16 As[128 * 32];
  __shared__ __attribute__((aligned(16))) bf16 Bs[128 * 32];
  const int tid = threadIdx.x;
  const int w = tid >> 6, lane = tid & 63;
  const int quad = lane >> 4, ln = lane & 15;
  const int m0 = blockIdx.y * 128, n0 = blockIdx.x * 128;
  const int wm = (w >> 1) * 64, wn = (w & 1) * 64;
  f32x4 acc[4][4] = {};

  for (int k0 = 0; k0 < DIM; k0 += 32) {
#pragma unroll
    for (int i = 0; i < 2; ++i) {
      const int c = i * 256 + tid;
      LDS_ASYNC16(A  + (size_t)(m0 + (c >> 2)) * DIM + k0 + (c & 3) * 8,
                  As + (size_t)(i * 256 + w * 64) * 8);
      LDS_ASYNC16(BT + (size_t)(n0 + (c >> 2)) * DIM + k0 + (c & 3) * 8,
                  Bs + (size_t)(i * 256 + w * 64) * 8);
    }
    __syncthreads();
    bf16x8 af[4], bfr[4];
#pragma unroll
    for (int t = 0; t < 4; ++t)
      af[t] = *(const bf16x8*)(As + (wm + t * 16 + ln) * 32 + quad * 8);
#pragma unroll
    for (int t = 0; t < 4; ++t)
      bfr[t] = *(const bf16x8*)(Bs + (wn + t * 16 + ln) * 32 + quad * 8);
#pragma unroll
    for (int mt = 0; mt < 4; ++mt)
#pragma unroll
      for (int nt = 0; nt < 4; ++nt)
        acc[mt][nt] = __builtin_amdgcn_mfma_f32_16x16x32_bf16(
            af[mt], bfr[nt], acc[mt][nt], 0, 0, 0);
    __syncthreads();
  }

  if (MODE == 0) {
    bf16* Co = (bf16*)C;
#pragma unroll
    for (int mt = 0; mt < 4; ++mt)
#pragma unroll
      for (int nt = 0; nt < 4; ++nt) {
        int gr = m0 + wm + mt * 16 + quad * 4;
        int gc = n0 + wn + nt * 16 + ln;
#pragma unroll
        for (int r = 0; r < 4; ++r)
          Co[(size_t)(gr + r) * DIM + gc] = (bf16)acc[mt][nt][r];
      }
  } else {
    float* Co = (float*)C;
#pragma unroll
    for (int mt = 0; mt < 4; ++mt)
#pragma unroll
      for (int nt = 0; nt < 4; ++nt) {
        int gr = m0 + wm + mt * 16 + quad * 4;
        int gc = n0 + wn + nt * 16 + ln;
#pragma unroll
        for (int r = 0; r < 4; ++r)
          Co[(size_t)(gr + r) * DIM + gc] = acc[mt][nt][r];
      }
  }
}

// ------------------------------------------------------- flash attn (split-K)
// Q (pre-scaled by QSC, exp2 domain), K row-major; VT (B,NH,HD,SEQ).
// Grid (24, B*NH): e<8 -> q-tile t=e, whole k-range (<=16 tiles), direct write.
// e>=8 -> t=8+((e-8)>>1), chunk c=(e-8)&1 of 16 k-tiles; writes bf16 partial
// O (unnormalized) + per-row m,l; flash_merge combines the two chunks.
constexpr int PSTR = 72;
__global__ __launch_bounds__(256, 3) void flash_attn(
    const bf16* __restrict__ Q, const bf16* __restrict__ K,
    const bf16* __restrict__ VT, bf16* __restrict__ O,
    bf16* __restrict__ Opart, float* __restrict__ Mpart,
    float* __restrict__ Lpart) {
  __shared__ __attribute__((aligned(16))) bf16 Ks[64 * 128];
  __shared__ __attribute__((aligned(16))) bf16 VTs[128 * 64];
  __shared__ __attribute__((aligned(16))) bf16 Ps[4][32 * PSTR];
  const int tid = threadIdx.x;
  const int w = tid >> 6, lane = tid & 63, quad = lane >> 4, ln = lane & 15;
  const int e = blockIdx.x;
  const int t = (e < 8) ? e : (8 + ((e - 8) >> 1));
  const int c0 = (e < 8) ? 0 : ((e - 8) & 1);
  const bool partial = (e >= 8);
  const int q0 = t * 128;
  const int ktN = 2 * (t + 1);
  const int kt0 = c0 * 16;
  const int kt1 = partial ? ((c0 == 0) ? 16 : ktN) : ktN;
  const int b = blockIdx.y >> 4, h = blockIdx.y & 15;

  bf16x8 qf[2][4];
#pragma unroll
  for (int mt = 0; mt < 2; ++mt)
#pragma unroll
    for (int kc = 0; kc < 4; ++kc)
      qf[mt][kc] = *(const bf16x8*)(Q + ((size_t)b * SEQ + q0 + w * 32 + mt * 16 + ln) * DIM +
                                    h * HD + kc * 32 + quad * 8);
  f32x4 o[2][8] = {};
  float mst[2][4], lst[2][4];
#pragma unroll
  for (int mt = 0; mt < 2; ++mt)
#pragma unroll
    for (int r = 0; r < 4; ++r) { mst[mt][r] = -1e30f; lst[mt][r] = 0.f; }

  for (int kt = kt0; kt < kt1; ++kt) {
    __syncthreads();
#pragma unroll
    for (int i = 0; i < 4; ++i) {
      const int c = i * 256 + tid;
      LDS_ASYNC16(K + ((size_t)b * SEQ + kt * 64 + (c >> 4)) * DIM + h * HD +
                      (((c & 15) ^ ((c >> 4) & 15)) * 8),
                  Ks + (size_t)(i * 256 + w * 64) * 8);
      LDS_ASYNC16(VT + ((size_t)((b * NH + h) * HD) + (c >> 3)) * SEQ + kt * 64 +
                      (((c & 7) ^ ((c >> 3) & 7)) * 8),
                  VTs + (size_t)(i * 256 + w * 64) * 8);
    }
    __syncthreads();

    // S = Q K^T (exp2 domain; scale pre-folded into Q)
    f32x4 s[2][4] = {};
#pragma unroll
    for (int nt = 0; nt < 4; ++nt) {
      bf16x8 kf[4];
#pragma unroll
      for (int kc = 0; kc < 4; ++kc)
        kf[kc] = *(const bf16x8*)(Ks + (nt * 16 + ln) * 128 +
                                  (((kc * 4 + quad) ^ ln) * 8));
#pragma unroll
      for (int kc = 0; kc < 4; ++kc)
#pragma unroll
        for (int mt = 0; mt < 2; ++mt)
          s[mt][nt] = __builtin_amdgcn_mfma_f32_16x16x32_bf16(
              qf[mt][kc], kf[kc], s[mt][nt], 0, 0, 0);
    }

    const bool diag = (kt * 64 + 63 > q0);
    if (diag) {
#pragma unroll
      for (int mt = 0; mt < 2; ++mt)
#pragma unroll
        for (int nt = 0; nt < 4; ++nt)
#pragma unroll
          for (int r = 0; r < 4; ++r) {
            int kg = kt * 64 + nt * 16 + ln;
            int qg = q0 + w * 32 + mt * 16 + quad * 4 + r;
            if (kg > qg) s[mt][nt][r] = -1e30f;
          }
    }

    // online softmax, exp2 domain; DPP 16-lane max (no LDS shuffles)
#pragma unroll
    for (int mt = 0; mt < 2; ++mt)
#pragma unroll
      for (int r = 0; r < 4; ++r) {
        float rm = fmaxf(fmaxf(s[mt][0][r], s[mt][1][r]),
                         fmaxf(s[mt][2][r], s[mt][3][r]));
        rm = rowmax16(rm);
        float mold = mst[mt][r];
        float mnew = fmaxf(mold, rm);
        float alpha = exp2f(mold - mnew);
        mst[mt][r] = mnew;
        float rs = 0.f;
#pragma unroll
        for (int nt = 0; nt < 4; ++nt) {
          float p = exp2f(s[mt][nt][r] - mnew);
          rs += p;
          Ps[w][(mt * 16 + quad * 4 + r) * PSTR + nt * 16 + ln] = (bf16)p;
        }
        lst[mt][r] = lst[mt][r] * alpha + rs;
#pragma unroll
        for (int nd = 0; nd < 8; ++nd) o[mt][nd][r] *= alpha;
      }
    __syncthreads();

    // O += P V
#pragma unroll
    for (int kc2 = 0; kc2 < 2; ++kc2) {
      bf16x8 pf[2];
#pragma unroll
      for (int mt = 0; mt < 2; ++mt)
        pf[mt] = *(const bf16x8*)(&Ps[w][(mt * 16 + ln) * PSTR + kc2 * 32 + quad * 8]);
#pragma unroll
      for (int nd = 0; nd < 8; ++nd) {
        bf16x8 vf = *(const bf16x8*)(VTs + (nd * 16 + ln) * 64 +
                                     (((kc2 * 4 + quad) ^ (ln & 7)) * 8));
#pragma unroll
        for (int mt = 0; mt < 2; ++mt)
          o[mt][nd] = __builtin_amdgcn_mfma_f32_16x16x32_bf16(
              pf[mt], vf, o[mt][nd], 0, 0, 0);
      }
    }
  }

  if (!partial) {
#pragma unroll
    for (int mt = 0; mt < 2; ++mt)
#pragma unroll
      for (int r = 0; r < 4; ++r) {
        float inv = 1.f / rowsum16(lst[mt][r]);
        int qg = q0 + w * 32 + mt * 16 + quad * 4 + r;
#pragma unroll
        for (int nd = 0; nd < 8; ++nd)
          O[((size_t)b * SEQ + qg) * DIM + h * HD + nd * 16 + ln] =
              (bf16)(o[mt][nd][r] * inv);
      }
  } else {
    const int slot = (((blockIdx.y << 3) + (t - 8)) << 1) + c0;
    bf16* Op = Opart + (size_t)slot * (128 * 128);
#pragma unroll
    for (int mt = 0; mt < 2; ++mt)
#pragma unroll
      for (int r = 0; r < 4; ++r) {
        float l = rowsum16(lst[mt][r]);
        int qr = w * 32 + mt * 16 + quad * 4 + r;
        if (ln == 0) {
          Mpart[slot * 128 + qr] = mst[mt][r];
          Lpart[slot * 128 + qr] = l;
        }
#pragma unroll
        for (int nd = 0; nd < 8; ++nd)
          Op[qr * 128 + nd * 16 + ln] = (bf16)o[mt][nd][r];
      }
  }
}

// ----------------------------------------------------- merge split-K partials
__global__ __launch_bounds__(256) void flash_merge(const bf16* __restrict__ Opart,
                                                   const float* __restrict__ Mpart,
                                                   const float* __restrict__ Lpart,
                                                   bf16* __restrict__ O) {
  const int g = blockIdx.x;  // bh*8 + (t-8)
  const int bh = g >> 3, t = 8 + (g & 7);
  const int b = bh >> 4, h = bh & 15;
  const int row = threadIdx.x >> 1, half = threadIdx.x & 1;
  const int s0 = g * 2, s1 = g * 2 + 1;
  float m0 = Mpart[s0 * 128 + row], m1 = Mpart[s1 * 128 + row];
  float l0 = Lpart[s0 * 128 + row], l1 = Lpart[s1 * 128 + row];
  float M = fmaxf(m0, m1);
  float w0 = exp2f(m0 - M), w1 = exp2f(m1 - M);
  float inv = 1.f / (w0 * l0 + w1 * l1);
  w0 *= inv; w1 *= inv;
  const bf16* p0 = Opart + (size_t)s0 * (128 * 128) + row * 128 + half * 64;
  const bf16* p1 = Opart + (size_t)s1 * (128 * 128) + row * 128 + half * 64;
  bf16* dst = O + ((size_t)b * SEQ + t * 128 + row) * DIM + h * HD + half * 64;
#pragma unroll
  for (int j = 0; j < 8; ++j) {
    bf16x8 a = *(const bf16x8*)(p0 + j * 8);
    bf16x8 c = *(const bf16x8*)(p1 + j * 8);
    bf16x8 o8;
#pragma unroll
    for (int k = 0; k < 8; ++k)
      o8[k] = (bf16)(w0 * (float)a[k] + w1 * (float)c[k]);
    *(bf16x8*)(dst + j * 8) = o8;
  }
}

// ------------------------------------------------------------------- launch
extern "C" void kernel_launch(void* const* d_in, const int* in_sizes, int n_in,
                              void* d_out, int out_size, void* d_ws, size_t ws_size,
                              hipStream_t stream) {
  (void)in_sizes; (void)n_in; (void)out_size; (void)ws_size;
  const float* x  = (const float*)d_in[0];
  const float* Wq = (const float*)d_in[1];
  const float* Wk = (const float*)d_in[2];
  const float* Wv = (const float*)d_in[3];
  const float* Wo = (const float*)d_in[4];

  char* ws = (char*)d_ws;
  const size_t MB = 1u << 20;
  const size_t WB = (size_t)DIM * DIM * 2;  // 8 MB
  bf16* WTqkv = (bf16*)(ws);                // 24 MB; dead after gemm_qkv
  bf16* WoT   = (bf16*)(ws + 3 * WB);       // 8 MB
  bf16* xb    = (bf16*)(ws + 32 * MB);      // 16 MB; Ab aliases after QKV
  bf16* Qb    = (bf16*)(ws + 48 * MB);
  bf16* Kb    = (bf16*)(ws + 64 * MB);
  bf16* VT    = (bf16*)(ws + 80 * MB);
  bf16* Ab    = xb;
  // split-K partial buffers alias the (dead) WTqkv region: 16 MB + 0.5 MB
  bf16*  Opart = (bf16*)(ws);
  float* Mpart = (float*)(ws + 16 * MB);
  float* Lpart = (float*)(ws + 16 * MB + 256 * 1024);

  int n4 = BATCH * SEQ * DIM / 4;
  cvt_f32_to_bf16<<<n4 / 256, 256, 0, stream>>>((const float4*)x, (bf16x4*)xb, n4);
  dim3 tb(32, 8), tg(DIM / 32, DIM / 32);
  transpose_w_bf16<<<tg, tb, 0, stream>>>(Wq, WTqkv);
  transpose_w_bf16<<<tg, tb, 0, stream>>>(Wk, WTqkv + (size_t)DIM * DIM);
  transpose_w_bf16<<<tg, tb, 0, stream>>>(Wv, WTqkv + 2 * (size_t)DIM * DIM);
  transpose_w_bf16<<<tg, tb, 0, stream>>>(Wo, WoT);

  dim3 qg(3 * DIM / 128, BATCH * SEQ / 128);  // 48 x 32
  gemm_qkv<<<qg, 256, 0, stream>>>(xb, WTqkv, Qb, Kb, VT);

  dim3 fg(24, BATCH * NH);
  flash_attn<<<fg, 256, 0, stream>>>(Qb, Kb, VT, Ab, Opart, Mpart, Lpart);
  flash_merge<<<256, 256, 0, stream>>>(Opart, Mpart, Lpart, Ab);

  dim3 gg(DIM / 128, BATCH * SEQ / 128);
  gemm_bt<2><<<gg, 256, 0, stream>>>(Ab, WoT, d_out);
}

// Round 4
// 469.441 us; speedup vs baseline: 1.6821x; 1.0229x over previous
//
#include <hip/hip_runtime.h>
#include <hip/hip_bf16.h>
#include <math.h>

typedef __bf16 bf16;
typedef __attribute__((ext_vector_type(2))) __bf16 bf16x2;
typedef __attribute__((ext_vector_type(4))) __bf16 bf16x4;
typedef __attribute__((ext_vector_type(8))) __bf16 bf16x8;
typedef __attribute__((ext_vector_type(4))) float f32x4;

#define LDS_ASYNC16(gptr, lptr)                                                        \
  __builtin_amdgcn_global_load_lds(                                                    \
      (const __attribute__((address_space(1))) void*)(gptr),                           \
      (__attribute__((address_space(3))) void*)(lptr), 16, 0, 0)

constexpr int BATCH = 2, SEQ = 2048, DIM = 2048, NH = 16, HD = 128;
// 1/sqrt(128) * log2(e): folded into Q at projection; flash works in exp2 domain
constexpr float QSC = 0.12751744f;
constexpr float FREQC = 0.20762050593046f;  // log2(10000)/64

// ---- DPP 16-lane reductions (row_ror rotates within 16-lane rows on gfx9) ----
template <int CTRL>
__device__ __forceinline__ float dpp_mov_f(float x) {
  return __int_as_float(__builtin_amdgcn_update_dpp(
      __float_as_int(x), __float_as_int(x), CTRL, 0xf, 0xf, false));
}
__device__ __forceinline__ float rowmax16(float x) {
  x = fmaxf(x, dpp_mov_f<0x121>(x));  // ror:1
  x = fmaxf(x, dpp_mov_f<0x122>(x));  // ror:2
  x = fmaxf(x, dpp_mov_f<0x124>(x));  // ror:4
  x = fmaxf(x, dpp_mov_f<0x128>(x));  // ror:8
  return x;
}
__device__ __forceinline__ float rowsum16(float x) {
  x += dpp_mov_f<0x121>(x);
  x += dpp_mov_f<0x122>(x);
  x += dpp_mov_f<0x124>(x);
  x += dpp_mov_f<0x128>(x);
  return x;
}

// ---------------------------------------------------------------- fp32 -> bf16
__global__ void cvt_f32_to_bf16(const float4* __restrict__ in,
                                bf16x4* __restrict__ out, int n4) {
  int i = blockIdx.x * blockDim.x + threadIdx.x;
  if (i >= n4) return;
  float4 v = in[i];
  bf16x4 o;
  o[0] = (bf16)v.x; o[1] = (bf16)v.y; o[2] = (bf16)v.z; o[3] = (bf16)v.w;
  out[i] = o;
}

// ------------------------- all 4 weights: W (K,N) fp32 -> W^T (N,K) bf16, z=which
__global__ void transpose_w4(const float* __restrict__ W0, const float* __restrict__ W1,
                             const float* __restrict__ W2, const float* __restrict__ W3,
                             bf16* __restrict__ T0, bf16* __restrict__ T3) {
  __shared__ float tile[32][33];
  const int z = blockIdx.z;
  const float* W = (z == 0) ? W0 : (z == 1) ? W1 : (z == 2) ? W2 : W3;
  bf16* WT = (z == 3) ? T3 : (T0 + (size_t)z * DIM * DIM);
  int tx = threadIdx.x, ty = threadIdx.y;
  int bx = blockIdx.x * 32, by = blockIdx.y * 32;
#pragma unroll
  for (int j = 0; j < 32; j += 8)
    tile[ty + j][tx] = W[(size_t)(by + ty + j) * DIM + bx + tx];
  __syncthreads();
#pragma unroll
  for (int j = 0; j < 32; j += 8)
    WT[(size_t)(bx + ty + j) * DIM + by + tx] = (bf16)tile[tx][ty + j];
}

// LDS chunk swizzle for GEMM staging/reads: slot (row, p) holds logical k-chunk
// p ^ ((row>>1)&3). Quarter-wave fragment reads then spread 2 lanes/bank-group
// (free) instead of 8-way conflicts at the naive layout.
__device__ __forceinline__ int swz_src(int c) {          // staging: logical chunk for slot c
  return (c & 3) ^ ((c >> 3) & 3);
}
__device__ __forceinline__ int swz_rd(int quad, int ln) { // read: phys chunk
  return quad ^ ((ln >> 1) & 3);
}

// ----------------------------------------------------- fused QKV GEMM + RoPE
// A[4096,2048] bf16, BT = [WqT;WkT;WvT] (6144,2048) bf16.
// n0<2048: Q (rope, *QSC, row-major); <4096: K (rope, row-major);
// else: V written as V^T (B,NH,HD,SEQ).
__global__ __launch_bounds__(256) void gemm_qkv(const bf16* __restrict__ A,
                                                const bf16* __restrict__ BT,
                                                bf16* __restrict__ Qb,
                                                bf16* __restrict__ Kb,
                                                bf16* __restrict__ VTo) {
  __shared__ __attribute__((aligned(16))) bf16 As[128 * 32];
  __shared__ __attribute__((aligned(16))) bf16 Bs[128 * 32];
  const int tid = threadIdx.x;
  const int w = tid >> 6, lane = tid & 63;
  const int quad = lane >> 4, ln = lane & 15;
  const int m0 = blockIdx.y * 128, n0 = blockIdx.x * 128;
  const int wm = (w >> 1) * 64, wn = (w & 1) * 64;
  const int rdc = swz_rd(quad, ln) * 8;
  f32x4 acc[4][4] = {};

  for (int k0 = 0; k0 < DIM; k0 += 32) {
#pragma unroll
    for (int i = 0; i < 2; ++i) {
      const int c = i * 256 + tid;
      LDS_ASYNC16(A  + (size_t)(m0 + (c >> 2)) * DIM + k0 + swz_src(c) * 8,
                  As + (size_t)(i * 256 + w * 64) * 8);
      LDS_ASYNC16(BT + (size_t)(n0 + (c >> 2)) * DIM + k0 + swz_src(c) * 8,
                  Bs + (size_t)(i * 256 + w * 64) * 8);
    }
    __syncthreads();
    bf16x8 af[4], bfr[4];
#pragma unroll
    for (int t = 0; t < 4; ++t)
      af[t] = *(const bf16x8*)(As + (wm + t * 16 + ln) * 32 + rdc);
#pragma unroll
    for (int t = 0; t < 4; ++t)
      bfr[t] = *(const bf16x8*)(Bs + (wn + t * 16 + ln) * 32 + rdc);
#pragma unroll
    for (int mt = 0; mt < 4; ++mt)
#pragma unroll
      for (int nt = 0; nt < 4; ++nt)
        acc[mt][nt] = __builtin_amdgcn_mfma_f32_16x16x32_bf16(
            af[mt], bfr[nt], acc[mt][nt], 0, 0, 0);
    __syncthreads();
  }

  const int sel = n0 >> 11;  // 0:Q 1:K 2:V  (block-uniform)
  if (sel == 2) {
#pragma unroll
    for (int mt = 0; mt < 4; ++mt)
#pragma unroll
      for (int nt = 0; nt < 4; ++nt) {
        int gr = m0 + wm + mt * 16 + quad * 4;
        int fc = (n0 + wn + nt * 16 + ln) & 2047;
        int b = gr >> 11, s0 = gr & (SEQ - 1);
        int h = fc >> 7, d = fc & (HD - 1);
        bf16x4 pk;
#pragma unroll
        for (int r = 0; r < 4; ++r) pk[r] = (bf16)acc[mt][nt][r];
        *(bf16x4*)(VTo + ((size_t)((b * NH + h) * HD + d)) * SEQ + s0) = pk;
      }
  } else {
    bf16* Dst = sel ? Kb : Qb;
    const float osc = sel ? 1.0f : QSC;
#pragma unroll
    for (int nt = 0; nt < 4; ++nt) {
      int gc = n0 + wn + nt * 16 + ln;
      int fc = gc & 2047, d = fc & (HD - 1);
      float freq = exp2f(-(float)(d >> 1) * FREQC);
      bool ev = !(d & 1);
#pragma unroll
      for (int mt = 0; mt < 4; ++mt) {
#pragma unroll
        for (int r = 0; r < 4; ++r) {
          int gr = m0 + wm + mt * 16 + quad * 4 + r;
          int s = gr & (SEQ - 1);
          float ang = (float)s * freq;
          float sn, cs;
          __sincosf(ang, &sn, &cs);
          float own = acc[mt][nt][r];
          float oth = __shfl_xor(own, 1);  // partner feature (d^1), lane ln^1
          float res = ev ? (own * cs - oth * sn) : (oth * sn + own * cs);
          Dst[(size_t)gr * DIM + fc] = (bf16)(res * osc);
        }
      }
    }
  }
}

// --------------------------------------------------------------------- GEMM
// C[M,N] = A * BT^T; MODE 2: C fp32 row-major (used for the Wo projection).
template <int MODE>
__global__ __launch_bounds__(256) void gemm_bt(const bf16* __restrict__ A,
                                               const bf16* __restrict__ BT,
                                               void* __restrict__ C) {
  __shared__ __attribute__((aligned(16))) bf16 As[128 * 32];
  __shared__ __attribute__((aligned(16))) bf16 Bs[128 * 32];
  const int tid = threadIdx.x;
  const int w = tid >> 6, lane = tid & 63;
  const int quad = lane >> 4, ln = lane & 15;
  const int m0 = blockIdx.y * 128, n0 = blockIdx.x * 128;
  const int wm = (w >> 1) * 64, wn = (w & 1) * 64;
  const int rdc = swz_rd(quad, ln) * 8;
  f32x4 acc[4][4] = {};

  for (int k0 = 0; k0 < DIM; k0 += 32) {
#pragma unroll
    for (int i = 0; i < 2; ++i) {
      const int c = i * 256 + tid;
      LDS_ASYNC16(A  + (size_t)(m0 + (c >> 2)) * DIM + k0 + swz_src(c) * 8,
                  As + (size_t)(i * 256 + w * 64) * 8);
      LDS_ASYNC16(BT + (size_t)(n0 + (c >> 2)) * DIM + k0 + swz_src(c) * 8,
                  Bs + (size_t)(i * 256 + w * 64) * 8);
    }
    __syncthreads();
    bf16x8 af[4], bfr[4];
#pragma unroll
    for (int t = 0; t < 4; ++t)
      af[t] = *(const bf16x8*)(As + (wm + t * 16 + ln) * 32 + rdc);
#pragma unroll
    for (int t = 0; t < 4; ++t)
      bfr[t] = *(const bf16x8*)(Bs + (wn + t * 16 + ln) * 32 + rdc);
#pragma unroll
    for (int mt = 0; mt < 4; ++mt)
#pragma unroll
      for (int nt = 0; nt < 4; ++nt)
        acc[mt][nt] = __builtin_amdgcn_mfma_f32_16x16x32_bf16(
            af[mt], bfr[nt], acc[mt][nt], 0, 0, 0);
    __syncthreads();
  }

  if (MODE == 0) {
    bf16* Co = (bf16*)C;
#pragma unroll
    for (int mt = 0; mt < 4; ++mt)
#pragma unroll
      for (int nt = 0; nt < 4; ++nt) {
        int gr = m0 + wm + mt * 16 + quad * 4;
        int gc = n0 + wn + nt * 16 + ln;
#pragma unroll
        for (int r = 0; r < 4; ++r)
          Co[(size_t)(gr + r) * DIM + gc] = (bf16)acc[mt][nt][r];
      }
  } else {
    float* Co = (float*)C;
#pragma unroll
    for (int mt = 0; mt < 4; ++mt)
#pragma unroll
      for (int nt = 0; nt < 4; ++nt) {
        int gr = m0 + wm + mt * 16 + quad * 4;
        int gc = n0 + wn + nt * 16 + ln;
#pragma unroll
        for (int r = 0; r < 4; ++r)
          Co[(size_t)(gr + r) * DIM + gc] = acc[mt][nt][r];
      }
  }
}

// ------------------------------------------------------- flash attn (split-K)
// Q (pre-scaled by QSC, exp2 domain), K row-major; VT (B,NH,HD,SEQ).
// Grid (24, B*NH): e<8 -> q-tile t=e, whole k-range (<=16 tiles), direct write.
// e>=8 -> t=8+((e-8)>>1), chunk c=(e-8)&1 of 16 k-tiles; writes bf16 partial
// O (unnormalized) + per-row m,l; flash_merge combines the two chunks.
constexpr int PSTR = 72;
__global__ __launch_bounds__(256, 3) void flash_attn(
    const bf16* __restrict__ Q, const bf16* __restrict__ K,
    const bf16* __restrict__ VT, bf16* __restrict__ O,
    bf16* __restrict__ Opart, float* __restrict__ Mpart,
    float* __restrict__ Lpart) {
  __shared__ __attribute__((aligned(16))) bf16 Ks[64 * 128];
  __shared__ __attribute__((aligned(16))) bf16 VTs[128 * 64];
  __shared__ __attribute__((aligned(16))) bf16 Ps[4][32 * PSTR];
  const int tid = threadIdx.x;
  const int w = tid >> 6, lane = tid & 63, quad = lane >> 4, ln = lane & 15;
  const int e = blockIdx.x;
  const int t = (e < 8) ? e : (8 + ((e - 8) >> 1));
  const int c0 = (e < 8) ? 0 : ((e - 8) & 1);
  const bool partial = (e >= 8);
  const int q0 = t * 128;
  const int ktN = 2 * (t + 1);
  const int kt0 = c0 * 16;
  const int kt1 = partial ? ((c0 == 0) ? 16 : ktN) : ktN;
  const int b = blockIdx.y >> 4, h = blockIdx.y & 15;

  bf16x8 qf[2][4];
#pragma unroll
  for (int mt = 0; mt < 2; ++mt)
#pragma unroll
    for (int kc = 0; kc < 4; ++kc)
      qf[mt][kc] = *(const bf16x8*)(Q + ((size_t)b * SEQ + q0 + w * 32 + mt * 16 + ln) * DIM +
                                    h * HD + kc * 32 + quad * 8);
  f32x4 o[2][8] = {};
  float mst[2][4], lst[2][4];
#pragma unroll
  for (int mt = 0; mt < 2; ++mt)
#pragma unroll
    for (int r = 0; r < 4; ++r) { mst[mt][r] = -1e30f; lst[mt][r] = 0.f; }

  for (int kt = kt0; kt < kt1; ++kt) {
    __syncthreads();
#pragma unroll
    for (int i = 0; i < 4; ++i) {
      const int c = i * 256 + tid;
      LDS_ASYNC16(K + ((size_t)b * SEQ + kt * 64 + (c >> 4)) * DIM + h * HD +
                      (((c & 15) ^ ((c >> 4) & 15)) * 8),
                  Ks + (size_t)(i * 256 + w * 64) * 8);
      LDS_ASYNC16(VT + ((size_t)((b * NH + h) * HD) + (c >> 3)) * SEQ + kt * 64 +
                      (((c & 7) ^ ((c >> 3) & 7)) * 8),
                  VTs + (size_t)(i * 256 + w * 64) * 8);
    }
    __syncthreads();

    // S = Q K^T (exp2 domain; scale pre-folded into Q)
    f32x4 s[2][4] = {};
#pragma unroll
    for (int nt = 0; nt < 4; ++nt) {
      bf16x8 kf[4];
#pragma unroll
      for (int kc = 0; kc < 4; ++kc)
        kf[kc] = *(const bf16x8*)(Ks + (nt * 16 + ln) * 128 +
                                  (((kc * 4 + quad) ^ ln) * 8));
#pragma unroll
      for (int kc = 0; kc < 4; ++kc)
#pragma unroll
        for (int mt = 0; mt < 2; ++mt)
          s[mt][nt] = __builtin_amdgcn_mfma_f32_16x16x32_bf16(
              qf[mt][kc], kf[kc], s[mt][nt], 0, 0, 0);
    }

    const bool diag = (kt * 64 + 63 > q0);
    if (diag) {
#pragma unroll
      for (int mt = 0; mt < 2; ++mt)
#pragma unroll
        for (int nt = 0; nt < 4; ++nt)
#pragma unroll
          for (int r = 0; r < 4; ++r) {
            int kg = kt * 64 + nt * 16 + ln;
            int qg = q0 + w * 32 + mt * 16 + quad * 4 + r;
            if (kg > qg) s[mt][nt][r] = -1e30f;
          }
    }

    // online softmax, exp2 domain; DPP 16-lane max (no LDS shuffles)
#pragma unroll
    for (int mt = 0; mt < 2; ++mt)
#pragma unroll
      for (int r = 0; r < 4; ++r) {
        float rm = fmaxf(fmaxf(s[mt][0][r], s[mt][1][r]),
                         fmaxf(s[mt][2][r], s[mt][3][r]));
        rm = rowmax16(rm);
        float mold = mst[mt][r];
        float mnew = fmaxf(mold, rm);
        float alpha = exp2f(mold - mnew);
        mst[mt][r] = mnew;
        float rs = 0.f;
#pragma unroll
        for (int nt = 0; nt < 4; ++nt) {
          float p = exp2f(s[mt][nt][r] - mnew);
          rs += p;
          Ps[w][(mt * 16 + quad * 4 + r) * PSTR + nt * 16 + ln] = (bf16)p;
        }
        lst[mt][r] = lst[mt][r] * alpha + rs;
#pragma unroll
        for (int nd = 0; nd < 8; ++nd) o[mt][nd][r] *= alpha;
      }
    __syncthreads();

    // O += P V
#pragma unroll
    for (int kc2 = 0; kc2 < 2; ++kc2) {
      bf16x8 pf[2];
#pragma unroll
      for (int mt = 0; mt < 2; ++mt)
        pf[mt] = *(const bf16x8*)(&Ps[w][(mt * 16 + ln) * PSTR + kc2 * 32 + quad * 8]);
#pragma unroll
      for (int nd = 0; nd < 8; ++nd) {
        bf16x8 vf = *(const bf16x8*)(VTs + (nd * 16 + ln) * 64 +
                                     (((kc2 * 4 + quad) ^ (ln & 7)) * 8));
#pragma unroll
        for (int mt = 0; mt < 2; ++mt)
          o[mt][nd] = __builtin_amdgcn_mfma_f32_16x16x32_bf16(
              pf[mt], vf, o[mt][nd], 0, 0, 0);
      }
    }
  }

  if (!partial) {
#pragma unroll
    for (int mt = 0; mt < 2; ++mt)
#pragma unroll
      for (int r = 0; r < 4; ++r) {
        float inv = 1.f / rowsum16(lst[mt][r]);
        int qg = q0 + w * 32 + mt * 16 + quad * 4 + r;
#pragma unroll
        for (int nd = 0; nd < 8; ++nd)
          O[((size_t)b * SEQ + qg) * DIM + h * HD + nd * 16 + ln] =
              (bf16)(o[mt][nd][r] * inv);
      }
  } else {
    const int slot = (((blockIdx.y << 3) + (t - 8)) << 1) + c0;
    bf16* Op = Opart + (size_t)slot * (128 * 128);
#pragma unroll
    for (int mt = 0; mt < 2; ++mt)
#pragma unroll
      for (int r = 0; r < 4; ++r) {
        float l = rowsum16(lst[mt][r]);
        int qr = w * 32 + mt * 16 + quad * 4 + r;
        if (ln == 0) {
          Mpart[slot * 128 + qr] = mst[mt][r];
          Lpart[slot * 128 + qr] = l;
        }
#pragma unroll
        for (int nd = 0; nd < 8; ++nd)
          Op[qr * 128 + nd * 16 + ln] = (bf16)o[mt][nd][r];
      }
  }
}

// ----------------------------------------------------- merge split-K partials
__global__ __launch_bounds__(256) void flash_merge(const bf16* __restrict__ Opart,
                                                   const float* __restrict__ Mpart,
                                                   const float* __restrict__ Lpart,
                                                   bf16* __restrict__ O) {
  const int g = blockIdx.x;  // bh*8 + (t-8)
  const int bh = g >> 3, t = 8 + (g & 7);
  const int b = bh >> 4, h = bh & 15;
  const int row = threadIdx.x >> 1, half = threadIdx.x & 1;
  const int s0 = g * 2, s1 = g * 2 + 1;
  float m0 = Mpart[s0 * 128 + row], m1 = Mpart[s1 * 128 + row];
  float l0 = Lpart[s0 * 128 + row], l1 = Lpart[s1 * 128 + row];
  float M = fmaxf(m0, m1);
  float w0 = exp2f(m0 - M), w1 = exp2f(m1 - M);
  float inv = 1.f / (w0 * l0 + w1 * l1);
  w0 *= inv; w1 *= inv;
  const bf16* p0 = Opart + (size_t)s0 * (128 * 128) + row * 128 + half * 64;
  const bf16* p1 = Opart + (size_t)s1 * (128 * 128) + row * 128 + half * 64;
  bf16* dst = O + ((size_t)b * SEQ + t * 128 + row) * DIM + h * HD + half * 64;
#pragma unroll
  for (int j = 0; j < 8; ++j) {
    bf16x8 a = *(const bf16x8*)(p0 + j * 8);
    bf16x8 c = *(const bf16x8*)(p1 + j * 8);
    bf16x8 o8;
#pragma unroll
    for (int k = 0; k < 8; ++k)
      o8[k] = (bf16)(w0 * (float)a[k] + w1 * (float)c[k]);
    *(bf16x8*)(dst + j * 8) = o8;
  }
}

// ------------------------------------------------------------------- launch
extern "C" void kernel_launch(void* const* d_in, const int* in_sizes, int n_in,
                              void* d_out, int out_size, void* d_ws, size_t ws_size,
                              hipStream_t stream) {
  (void)in_sizes; (void)n_in; (void)out_size; (void)ws_size;
  const float* x  = (const float*)d_in[0];
  const float* Wq = (const float*)d_in[1];
  const float* Wk = (const float*)d_in[2];
  const float* Wv = (const float*)d_in[3];
  const float* Wo = (const float*)d_in[4];

  char* ws = (char*)d_ws;
  const size_t MB = 1u << 20;
  const size_t WB = (size_t)DIM * DIM * 2;  // 8 MB
  bf16* WTqkv = (bf16*)(ws);                // 24 MB; dead after gemm_qkv
  bf16* WoT   = (bf16*)(ws + 3 * WB);       // 8 MB
  bf16* xb    = (bf16*)(ws + 32 * MB);      // 16 MB; Ab aliases after QKV
  bf16* Qb    = (bf16*)(ws + 48 * MB);
  bf16* Kb    = (bf16*)(ws + 64 * MB);
  bf16* VT    = (bf16*)(ws + 80 * MB);
  bf16* Ab    = xb;
  // split-K partial buffers alias the (dead) WTqkv region: 16 MB + 0.5 MB
  bf16*  Opart = (bf16*)(ws);
  float* Mpart = (float*)(ws + 16 * MB);
  float* Lpart = (float*)(ws + 16 * MB + 256 * 1024);

  int n4 = BATCH * SEQ * DIM / 4;
  cvt_f32_to_bf16<<<n4 / 256, 256, 0, stream>>>((const float4*)x, (bf16x4*)xb, n4);
  dim3 tb(32, 8), tg(DIM / 32, DIM / 32, 4);
  transpose_w4<<<tg, tb, 0, stream>>>(Wq, Wk, Wv, Wo, WTqkv, WoT);

  dim3 qg(3 * DIM / 128, BATCH * SEQ / 128);  // 48 x 32
  gemm_qkv<<<qg, 256, 0, stream>>>(xb, WTqkv, Qb, Kb, VT);

  dim3 fg(24, BATCH * NH);
  flash_attn<<<fg, 256, 0, stream>>>(Qb, Kb, VT, Ab, Opart, Mpart, Lpart);
  flash_merge<<<256, 256, 0, stream>>>(Opart, Mpart, Lpart, Ab);

  dim3 gg(DIM / 128, BATCH * SEQ / 128);
  gemm_bt<2><<<gg, 256, 0, stream>>>(Ab, WoT, d_out);
}

// Round 5
// 461.705 us; speedup vs baseline: 1.7103x; 1.0168x over previous
//
#include <hip/hip_runtime.h>
#include <hip/hip_bf16.h>
#include <math.h>

typedef __bf16 bf16;
typedef __attribute__((ext_vector_type(2))) __bf16 bf16x2;
typedef __attribute__((ext_vector_type(4))) __bf16 bf16x4;
typedef __attribute__((ext_vector_type(8))) __bf16 bf16x8;
typedef __attribute__((ext_vector_type(4))) float f32x4;

#define LDS_ASYNC16(gptr, lptr)                                                        \
  __builtin_amdgcn_global_load_lds(                                                    \
      (const __attribute__((address_space(1))) void*)(gptr),                           \
      (__attribute__((address_space(3))) void*)(lptr), 16, 0, 0)

constexpr int BATCH = 2, SEQ = 2048, DIM = 2048, NH = 16, HD = 128;
// 1/sqrt(128) * log2(e): folded into Q at projection; flash works in exp2 domain
constexpr float QSC = 0.12751744f;
constexpr float FREQC = 0.20762050593046f;  // log2(10000)/64

// ---- DPP 16-lane reductions (row_ror rotates within 16-lane rows on gfx9) ----
template <int CTRL>
__device__ __forceinline__ float dpp_mov_f(float x) {
  return __int_as_float(__builtin_amdgcn_update_dpp(
      __float_as_int(x), __float_as_int(x), CTRL, 0xf, 0xf, false));
}
__device__ __forceinline__ float rowmax16(float x) {
  x = fmaxf(x, dpp_mov_f<0x121>(x));  // ror:1
  x = fmaxf(x, dpp_mov_f<0x122>(x));  // ror:2
  x = fmaxf(x, dpp_mov_f<0x124>(x));  // ror:4
  x = fmaxf(x, dpp_mov_f<0x128>(x));  // ror:8
  return x;
}
__device__ __forceinline__ float rowsum16(float x) {
  x += dpp_mov_f<0x121>(x);
  x += dpp_mov_f<0x122>(x);
  x += dpp_mov_f<0x124>(x);
  x += dpp_mov_f<0x128>(x);
  return x;
}

// ---------------------------------------------------------------- fp32 -> bf16
__global__ void cvt_f32_to_bf16(const float4* __restrict__ in,
                                bf16x4* __restrict__ out, int n4) {
  int i = blockIdx.x * blockDim.x + threadIdx.x;
  if (i >= n4) return;
  float4 v = in[i];
  bf16x4 o;
  o[0] = (bf16)v.x; o[1] = (bf16)v.y; o[2] = (bf16)v.z; o[3] = (bf16)v.w;
  out[i] = o;
}

// ------------------------- all 4 weights: W (K,N) fp32 -> W^T (N,K) bf16, z=which
__global__ void transpose_w4(const float* __restrict__ W0, const float* __restrict__ W1,
                             const float* __restrict__ W2, const float* __restrict__ W3,
                             bf16* __restrict__ T0, bf16* __restrict__ T3) {
  __shared__ float tile[32][33];
  const int z = blockIdx.z;
  const float* W = (z == 0) ? W0 : (z == 1) ? W1 : (z == 2) ? W2 : W3;
  bf16* WT = (z == 3) ? T3 : (T0 + (size_t)z * DIM * DIM);
  int tx = threadIdx.x, ty = threadIdx.y;
  int bx = blockIdx.x * 32, by = blockIdx.y * 32;
#pragma unroll
  for (int j = 0; j < 32; j += 8)
    tile[ty + j][tx] = W[(size_t)(by + ty + j) * DIM + bx + tx];
  __syncthreads();
#pragma unroll
  for (int j = 0; j < 32; j += 8)
    WT[(size_t)(bx + ty + j) * DIM + by + tx] = (bf16)tile[tx][ty + j];
}

// BK=64 GEMM LDS swizzle: row has 8 16B-chunks; slot (row,p) holds logical
// chunk p ^ (row&7). Quarter-wave b128 reads spread 2 lanes/bank-group (free).

// ----------------------------------------------------- fused QKV GEMM + RoPE
// A[4096,2048] bf16, BT = [WqT;WkT;WvT] (6144,2048) bf16.
// n0<2048: Q (rope, *QSC, row-major); <4096: K (rope, row-major);
// else: V written as V^T (B,NH,HD,SEQ).
__global__ __launch_bounds__(256) void gemm_qkv(const bf16* __restrict__ A,
                                                const bf16* __restrict__ BT,
                                                bf16* __restrict__ Qb,
                                                bf16* __restrict__ Kb,
                                                bf16* __restrict__ VTo) {
  __shared__ __attribute__((aligned(16))) bf16 As[128 * 64];
  __shared__ __attribute__((aligned(16))) bf16 Bs[128 * 64];
  const int tid = threadIdx.x;
  const int w = tid >> 6, lane = tid & 63;
  const int quad = lane >> 4, ln = lane & 15;
  const int m0 = blockIdx.y * 128, n0 = blockIdx.x * 128;
  const int wm = (w >> 1) * 64, wn = (w & 1) * 64;
  const int l7 = ln & 7;
  f32x4 acc[4][4] = {};

  for (int k0 = 0; k0 < DIM; k0 += 64) {
#pragma unroll
    for (int i = 0; i < 4; ++i) {
      const int c = i * 256 + tid;  // slot: row=c>>3, phys chunk p=c&7
      const int row = c >> 3, p = c & 7;
      LDS_ASYNC16(A  + (size_t)(m0 + row) * DIM + k0 + ((p ^ (row & 7)) * 8),
                  As + (size_t)(i * 256 + w * 64) * 8);
      LDS_ASYNC16(BT + (size_t)(n0 + row) * DIM + k0 + ((p ^ (row & 7)) * 8),
                  Bs + (size_t)(i * 256 + w * 64) * 8);
    }
    __syncthreads();
#pragma unroll
    for (int kh = 0; kh < 2; ++kh) {
      bf16x8 af[4], bfr[4];
#pragma unroll
      for (int t = 0; t < 4; ++t)
        af[t] = *(const bf16x8*)(As + (wm + t * 16 + ln) * 64 +
                                 (((kh * 4 + quad) ^ l7) * 8));
#pragma unroll
      for (int t = 0; t < 4; ++t)
        bfr[t] = *(const bf16x8*)(Bs + (wn + t * 16 + ln) * 64 +
                                  (((kh * 4 + quad) ^ l7) * 8));
#pragma unroll
      for (int mt = 0; mt < 4; ++mt)
#pragma unroll
        for (int nt = 0; nt < 4; ++nt)
          acc[mt][nt] = __builtin_amdgcn_mfma_f32_16x16x32_bf16(
              af[mt], bfr[nt], acc[mt][nt], 0, 0, 0);
    }
    __syncthreads();
  }

  const int sel = n0 >> 11;  // 0:Q 1:K 2:V  (block-uniform)
  if (sel == 2) {
#pragma unroll
    for (int mt = 0; mt < 4; ++mt)
#pragma unroll
      for (int nt = 0; nt < 4; ++nt) {
        int gr = m0 + wm + mt * 16 + quad * 4;
        int fc = (n0 + wn + nt * 16 + ln) & 2047;
        int b = gr >> 11, s0 = gr & (SEQ - 1);
        int h = fc >> 7, d = fc & (HD - 1);
        bf16x4 pk;
#pragma unroll
        for (int r = 0; r < 4; ++r) pk[r] = (bf16)acc[mt][nt][r];
        *(bf16x4*)(VTo + ((size_t)((b * NH + h) * HD + d)) * SEQ + s0) = pk;
      }
  } else {
    bf16* Dst = sel ? Kb : Qb;
    const float osc = sel ? 1.0f : QSC;
#pragma unroll
    for (int nt = 0; nt < 4; ++nt) {
      int gc = n0 + wn + nt * 16 + ln;
      int fc = gc & 2047, d = fc & (HD - 1);
      float freq = exp2f(-(float)(d >> 1) * FREQC);
      bool ev = !(d & 1);
#pragma unroll
      for (int mt = 0; mt < 4; ++mt) {
#pragma unroll
        for (int r = 0; r < 4; ++r) {
          int gr = m0 + wm + mt * 16 + quad * 4 + r;
          int s = gr & (SEQ - 1);
          float ang = (float)s * freq;
          float sn, cs;
          __sincosf(ang, &sn, &cs);
          float own = acc[mt][nt][r];
          float oth = __shfl_xor(own, 1);  // partner feature (d^1), lane ln^1
          float res = ev ? (own * cs - oth * sn) : (oth * sn + own * cs);
          Dst[(size_t)gr * DIM + fc] = (bf16)(res * osc);
        }
      }
    }
  }
}

// --------------------------------------------------------------------- GEMM
// C[M,N] = A * BT^T; MODE 2: C fp32 row-major (used for the Wo projection).
template <int MODE>
__global__ __launch_bounds__(256) void gemm_bt(const bf16* __restrict__ A,
                                               const bf16* __restrict__ BT,
                                               void* __restrict__ C) {
  __shared__ __attribute__((aligned(16))) bf16 As[128 * 64];
  __shared__ __attribute__((aligned(16))) bf16 Bs[128 * 64];
  const int tid = threadIdx.x;
  const int w = tid >> 6, lane = tid & 63;
  const int quad = lane >> 4, ln = lane & 15;
  const int m0 = blockIdx.y * 128, n0 = blockIdx.x * 128;
  const int wm = (w >> 1) * 64, wn = (w & 1) * 64;
  const int l7 = ln & 7;
  f32x4 acc[4][4] = {};

  for (int k0 = 0; k0 < DIM; k0 += 64) {
#pragma unroll
    for (int i = 0; i < 4; ++i) {
      const int c = i * 256 + tid;
      const int row = c >> 3, p = c & 7;
      LDS_ASYNC16(A  + (size_t)(m0 + row) * DIM + k0 + ((p ^ (row & 7)) * 8),
                  As + (size_t)(i * 256 + w * 64) * 8);
      LDS_ASYNC16(BT + (size_t)(n0 + row) * DIM + k0 + ((p ^ (row & 7)) * 8),
                  Bs + (size_t)(i * 256 + w * 64) * 8);
    }
    __syncthreads();
#pragma unroll
    for (int kh = 0; kh < 2; ++kh) {
      bf16x8 af[4], bfr[4];
#pragma unroll
      for (int t = 0; t < 4; ++t)
        af[t] = *(const bf16x8*)(As + (wm + t * 16 + ln) * 64 +
                                 (((kh * 4 + quad) ^ l7) * 8));
#pragma unroll
      for (int t = 0; t < 4; ++t)
        bfr[t] = *(const bf16x8*)(Bs + (wn + t * 16 + ln) * 64 +
                                  (((kh * 4 + quad) ^ l7) * 8));
#pragma unroll
      for (int mt = 0; mt < 4; ++mt)
#pragma unroll
        for (int nt = 0; nt < 4; ++nt)
          acc[mt][nt] = __builtin_amdgcn_mfma_f32_16x16x32_bf16(
              af[mt], bfr[nt], acc[mt][nt], 0, 0, 0);
    }
    __syncthreads();
  }

  if (MODE == 0) {
    bf16* Co = (bf16*)C;
#pragma unroll
    for (int mt = 0; mt < 4; ++mt)
#pragma unroll
      for (int nt = 0; nt < 4; ++nt) {
        int gr = m0 + wm + mt * 16 + quad * 4;
        int gc = n0 + wn + nt * 16 + ln;
#pragma unroll
        for (int r = 0; r < 4; ++r)
          Co[(size_t)(gr + r) * DIM + gc] = (bf16)acc[mt][nt][r];
      }
  } else {
    float* Co = (float*)C;
#pragma unroll
    for (int mt = 0; mt < 4; ++mt)
#pragma unroll
      for (int nt = 0; nt < 4; ++nt) {
        int gr = m0 + wm + mt * 16 + quad * 4;
        int gc = n0 + wn + nt * 16 + ln;
#pragma unroll
        for (int r = 0; r < 4; ++r)
          Co[(size_t)(gr + r) * DIM + gc] = acc[mt][nt][r];
      }
  }
}

// -------------------------- flash split-K chunk bookkeeping (chunk = 10 k-tiles)
// Per (b,h): t=0..4 direct (1 chunk); t=5..9: 2 chunks; t=10..14: 3; t=15: 4.
// 34 blocks/bh. Chunk 0 of a chunked tile writes unnormalized bf16 into O's
// final location; chunks >=1 go to Opart. All chunks write M/L.
__device__ __forceinline__ int ml_off(int t) {  // per-bh M/L slot base, stride 29
  return (t < 10) ? 2 * (t - 5) : (t < 15) ? 10 + 3 * (t - 10) : 25;
}
__device__ __forceinline__ int op_off(int t) {  // per-bh Opart slot base, stride 18
  return (t < 10) ? (t - 5) : (t < 15) ? 5 + 2 * (t - 10) : 15;
}

constexpr int PSTR = 72;
__global__ __launch_bounds__(256, 3) void flash_attn(
    const bf16* __restrict__ Q, const bf16* __restrict__ K,
    const bf16* __restrict__ VT, bf16* __restrict__ O,
    bf16* __restrict__ Opart, float* __restrict__ Mpart,
    float* __restrict__ Lpart) {
  __shared__ __attribute__((aligned(16))) bf16 Ks[64 * 128];
  __shared__ __attribute__((aligned(16))) bf16 VTs[128 * 64];
  __shared__ __attribute__((aligned(16))) bf16 Ps[4][32 * PSTR];
  const int tid = threadIdx.x;
  const int w = tid >> 6, lane = tid & 63, quad = lane >> 4, ln = lane & 15;
  const int e = blockIdx.x;  // 0..33
  int t, c0, nc;
  if (e < 5)       { t = e;                  c0 = 0;               nc = 1; }
  else if (e < 15) { t = 5 + ((e - 5) >> 1); c0 = (e - 5) & 1;     nc = 2; }
  else if (e < 30) { int q = (e - 15) / 3;   t = 10 + q; c0 = (e - 15) - 3 * q; nc = 3; }
  else             { t = 15;                 c0 = e - 30;          nc = 4; }
  const int q0 = t * 128;
  const int ktN = 2 * (t + 1);
  const int kt0 = c0 * 10;
  const int kt1 = min(kt0 + 10, ktN);
  const bool chunked = (nc > 1);
  const int bh = blockIdx.y;
  const int b = bh >> 4, h = bh & 15;

  bf16x8 qf[2][4];
#pragma unroll
  for (int mt = 0; mt < 2; ++mt)
#pragma unroll
    for (int kc = 0; kc < 4; ++kc)
      qf[mt][kc] = *(const bf16x8*)(Q + ((size_t)b * SEQ + q0 + w * 32 + mt * 16 + ln) * DIM +
                                    h * HD + kc * 32 + quad * 8);
  f32x4 o[2][8] = {};
  float mst[2][4], lst[2][4];
#pragma unroll
  for (int mt = 0; mt < 2; ++mt)
#pragma unroll
    for (int r = 0; r < 4; ++r) { mst[mt][r] = -1e30f; lst[mt][r] = 0.f; }

  for (int kt = kt0; kt < kt1; ++kt) {
    __syncthreads();
#pragma unroll
    for (int i = 0; i < 4; ++i) {
      const int c = i * 256 + tid;
      LDS_ASYNC16(K + ((size_t)b * SEQ + kt * 64 + (c >> 4)) * DIM + h * HD +
                      (((c & 15) ^ ((c >> 4) & 15)) * 8),
                  Ks + (size_t)(i * 256 + w * 64) * 8);
      LDS_ASYNC16(VT + ((size_t)((b * NH + h) * HD) + (c >> 3)) * SEQ + kt * 64 +
                      (((c & 7) ^ ((c >> 3) & 7)) * 8),
                  VTs + (size_t)(i * 256 + w * 64) * 8);
    }
    __syncthreads();

    // S = Q K^T (exp2 domain; scale pre-folded into Q)
    f32x4 s[2][4] = {};
#pragma unroll
    for (int nt = 0; nt < 4; ++nt) {
      bf16x8 kf[4];
#pragma unroll
      for (int kc = 0; kc < 4; ++kc)
        kf[kc] = *(const bf16x8*)(Ks + (nt * 16 + ln) * 128 +
                                  (((kc * 4 + quad) ^ ln) * 8));
#pragma unroll
      for (int kc = 0; kc < 4; ++kc)
#pragma unroll
        for (int mt = 0; mt < 2; ++mt)
          s[mt][nt] = __builtin_amdgcn_mfma_f32_16x16x32_bf16(
              qf[mt][kc], kf[kc], s[mt][nt], 0, 0, 0);
    }

    const bool diag = (kt * 64 + 63 > q0);
    if (diag) {
#pragma unroll
      for (int mt = 0; mt < 2; ++mt)
#pragma unroll
        for (int nt = 0; nt < 4; ++nt)
#pragma unroll
          for (int r = 0; r < 4; ++r) {
            int kg = kt * 64 + nt * 16 + ln;
            int qg = q0 + w * 32 + mt * 16 + quad * 4 + r;
            if (kg > qg) s[mt][nt][r] = -1e30f;
          }
    }

    // online softmax, exp2 domain; DPP 16-lane max (no LDS shuffles)
#pragma unroll
    for (int mt = 0; mt < 2; ++mt)
#pragma unroll
      for (int r = 0; r < 4; ++r) {
        float rm = fmaxf(fmaxf(s[mt][0][r], s[mt][1][r]),
                         fmaxf(s[mt][2][r], s[mt][3][r]));
        rm = rowmax16(rm);
        float mold = mst[mt][r];
        float mnew = fmaxf(mold, rm);
        float alpha = exp2f(mold - mnew);
        mst[mt][r] = mnew;
        float rs = 0.f;
#pragma unroll
        for (int nt = 0; nt < 4; ++nt) {
          float p = exp2f(s[mt][nt][r] - mnew);
          rs += p;
          Ps[w][(mt * 16 + quad * 4 + r) * PSTR + nt * 16 + ln] = (bf16)p;
        }
        lst[mt][r] = lst[mt][r] * alpha + rs;
#pragma unroll
        for (int nd = 0; nd < 8; ++nd) o[mt][nd][r] *= alpha;
      }
    __syncthreads();

    // O += P V
#pragma unroll
    for (int kc2 = 0; kc2 < 2; ++kc2) {
      bf16x8 pf[2];
#pragma unroll
      for (int mt = 0; mt < 2; ++mt)
        pf[mt] = *(const bf16x8*)(&Ps[w][(mt * 16 + ln) * PSTR + kc2 * 32 + quad * 8]);
#pragma unroll
      for (int nd = 0; nd < 8; ++nd) {
        bf16x8 vf = *(const bf16x8*)(VTs + (nd * 16 + ln) * 64 +
                                     (((kc2 * 4 + quad) ^ (ln & 7)) * 8));
#pragma unroll
        for (int mt = 0; mt < 2; ++mt)
          o[mt][nd] = __builtin_amdgcn_mfma_f32_16x16x32_bf16(
              pf[mt], vf, o[mt][nd], 0, 0, 0);
      }
    }
  }

  if (!chunked) {
#pragma unroll
    for (int mt = 0; mt < 2; ++mt)
#pragma unroll
      for (int r = 0; r < 4; ++r) {
        float inv = 1.f / rowsum16(lst[mt][r]);
        int qg = q0 + w * 32 + mt * 16 + quad * 4 + r;
#pragma unroll
        for (int nd = 0; nd < 8; ++nd)
          O[((size_t)b * SEQ + qg) * DIM + h * HD + nd * 16 + ln] =
              (bf16)(o[mt][nd][r] * inv);
      }
  } else {
    const int mls = bh * 29 + ml_off(t) + c0;
    bf16* Op = (c0 == 0) ? nullptr
                         : Opart + (size_t)(bh * 18 + op_off(t) + (c0 - 1)) * (128 * 128);
#pragma unroll
    for (int mt = 0; mt < 2; ++mt)
#pragma unroll
      for (int r = 0; r < 4; ++r) {
        float l = rowsum16(lst[mt][r]);
        int qr = w * 32 + mt * 16 + quad * 4 + r;
        if (ln == 0) {
          Mpart[mls * 128 + qr] = mst[mt][r];
          Lpart[mls * 128 + qr] = l;
        }
        if (c0 == 0) {
#pragma unroll
          for (int nd = 0; nd < 8; ++nd)
            O[((size_t)b * SEQ + q0 + qr) * DIM + h * HD + nd * 16 + ln] =
                (bf16)o[mt][nd][r];
        } else {
#pragma unroll
          for (int nd = 0; nd < 8; ++nd)
            Op[qr * 128 + nd * 16 + ln] = (bf16)o[mt][nd][r];
        }
      }
  }
}

// ----------------------------------------------------- merge split-K partials
// grid (32, 11): bh x (t-5). Chunk 0 lives unnormalized in O; chunks 1..nc-1
// in Opart. Combine with max-rebased weights, normalize, write O.
__global__ __launch_bounds__(256) void flash_merge(const bf16* __restrict__ Opart,
                                                   const float* __restrict__ Mpart,
                                                   const float* __restrict__ Lpart,
                                                   bf16* __restrict__ O) {
  const int bh = blockIdx.x;
  const int t = 5 + blockIdx.y;
  const int nc = (t < 10) ? 2 : (t < 15) ? 3 : 4;
  const int b = bh >> 4, h = bh & 15;
  const int row = threadIdx.x >> 1, half = threadIdx.x & 1;
  const int mlb = bh * 29 + ml_off(t);
  float m[4], l[4], wt[4];
  float M = -1e30f;
  for (int c = 0; c < nc; ++c) {
    m[c] = Mpart[(mlb + c) * 128 + row];
    l[c] = Lpart[(mlb + c) * 128 + row];
    M = fmaxf(M, m[c]);
  }
  float wsum = 0.f;
  for (int c = 0; c < nc; ++c) { wt[c] = exp2f(m[c] - M); wsum += wt[c] * l[c]; }
  const float inv = 1.f / wsum;
  bf16* dst = O + ((size_t)b * SEQ + t * 128 + row) * DIM + h * HD + half * 64;
  const bf16* pb = Opart + (size_t)(bh * 18 + op_off(t)) * (128 * 128) + row * 128 + half * 64;
#pragma unroll
  for (int j = 0; j < 8; ++j) {
    bf16x8 a0 = *(const bf16x8*)(dst + j * 8);
    float acc[8];
#pragma unroll
    for (int k = 0; k < 8; ++k) acc[k] = wt[0] * (float)a0[k];
    for (int c = 1; c < nc; ++c) {
      bf16x8 a = *(const bf16x8*)(pb + (size_t)(c - 1) * (128 * 128) + j * 8);
#pragma unroll
      for (int k = 0; k < 8; ++k) acc[k] += wt[c] * (float)a[k];
    }
    bf16x8 o8;
#pragma unroll
    for (int k = 0; k < 8; ++k) o8[k] = (bf16)(acc[k] * inv);
    *(bf16x8*)(dst + j * 8) = o8;
  }
}

// ------------------------------------------------------------------- launch
extern "C" void kernel_launch(void* const* d_in, const int* in_sizes, int n_in,
                              void* d_out, int out_size, void* d_ws, size_t ws_size,
                              hipStream_t stream) {
  (void)in_sizes; (void)n_in; (void)out_size; (void)ws_size;
  const float* x  = (const float*)d_in[0];
  const float* Wq = (const float*)d_in[1];
  const float* Wk = (const float*)d_in[2];
  const float* Wv = (const float*)d_in[3];
  const float* Wo = (const float*)d_in[4];

  char* ws = (char*)d_ws;
  const size_t MB = 1u << 20;
  const size_t WB = (size_t)DIM * DIM * 2;  // 8 MB
  bf16* WTqkv = (bf16*)(ws);                // 24 MB; dead after gemm_qkv
  bf16* WoT   = (bf16*)(ws + 3 * WB);       // 8 MB
  bf16* xb    = (bf16*)(ws + 32 * MB);      // 16 MB; Ab aliases after QKV
  bf16* Qb    = (bf16*)(ws + 48 * MB);
  bf16* Kb    = (bf16*)(ws + 64 * MB);
  bf16* VT    = (bf16*)(ws + 80 * MB);
  bf16* Ab    = xb;
  // split-K partials alias the (dead) WTqkv region:
  // Opart 18.9 MB (32 bh x 18 slots x 32 KB) + M/L ~0.5 MB each
  bf16*  Opart = (bf16*)(ws);
  float* Mpart = (float*)(ws + 19 * MB);
  float* Lpart = (float*)(ws + 19 * MB + 512 * 1024);

  int n4 = BATCH * SEQ * DIM / 4;
  cvt_f32_to_bf16<<<n4 / 256, 256, 0, stream>>>((const float4*)x, (bf16x4*)xb, n4);
  dim3 tb(32, 8), tg(DIM / 32, DIM / 32, 4);
  transpose_w4<<<tg, tb, 0, stream>>>(Wq, Wk, Wv, Wo, WTqkv, WoT);

  dim3 qg(3 * DIM / 128, BATCH * SEQ / 128);  // 48 x 32
  gemm_qkv<<<qg, 256, 0, stream>>>(xb, WTqkv, Qb, Kb, VT);

  dim3 fg(34, BATCH * NH);
  flash_attn<<<fg, 256, 0, stream>>>(Qb, Kb, VT, Ab, Opart, Mpart, Lpart);
  dim3 mg(BATCH * NH, 11);
  flash_merge<<<mg, 256, 0, stream>>>(Opart, Mpart, Lpart, Ab);

  dim3 gg(DIM / 128, BATCH * SEQ / 128);
  gemm_bt<2><<<gg, 256, 0, stream>>>(Ab, WoT, d_out);
}

// Round 6
// 451.686 us; speedup vs baseline: 1.7482x; 1.0222x over previous
//
#include <hip/hip_runtime.h>
#include <hip/hip_bf16.h>
#include <math.h>

typedef __bf16 bf16;
typedef __attribute__((ext_vector_type(2))) __bf16 bf16x2;
typedef __attribute__((ext_vector_type(4))) __bf16 bf16x4;
typedef __attribute__((ext_vector_type(8))) __bf16 bf16x8;
typedef __attribute__((ext_vector_type(4))) float f32x4;

#define LDS_ASYNC16(gptr, lptr)                                                        \
  __builtin_amdgcn_global_load_lds(                                                    \
      (const __attribute__((address_space(1))) void*)(gptr),                           \
      (__attribute__((address_space(3))) void*)(lptr), 16, 0, 0)

constexpr int BATCH = 2, SEQ = 2048, DIM = 2048, NH = 16, HD = 128;
// 1/sqrt(128) * log2(e): folded into Q at projection; flash works in exp2 domain
constexpr float QSC = 0.12751744f;
constexpr float FREQC = 0.20762050593046f;  // log2(10000)/64

// ---- DPP 16-lane reductions (row_ror rotates within 16-lane rows on gfx9) ----
template <int CTRL>
__device__ __forceinline__ float dpp_mov_f(float x) {
  return __int_as_float(__builtin_amdgcn_update_dpp(
      __float_as_int(x), __float_as_int(x), CTRL, 0xf, 0xf, false));
}
__device__ __forceinline__ float rowmax16(float x) {
  x = fmaxf(x, dpp_mov_f<0x121>(x));  // ror:1
  x = fmaxf(x, dpp_mov_f<0x122>(x));  // ror:2
  x = fmaxf(x, dpp_mov_f<0x124>(x));  // ror:4
  x = fmaxf(x, dpp_mov_f<0x128>(x));  // ror:8
  return x;
}
__device__ __forceinline__ float rowsum16(float x) {
  x += dpp_mov_f<0x121>(x);
  x += dpp_mov_f<0x122>(x);
  x += dpp_mov_f<0x124>(x);
  x += dpp_mov_f<0x128>(x);
  return x;
}

// ---------------------------------------------------------------- fp32 -> bf16
__global__ void cvt_f32_to_bf16(const float4* __restrict__ in,
                                bf16x4* __restrict__ out, int n4) {
  int i = blockIdx.x * blockDim.x + threadIdx.x;
  if (i >= n4) return;
  float4 v = in[i];
  bf16x4 o;
  o[0] = (bf16)v.x; o[1] = (bf16)v.y; o[2] = (bf16)v.z; o[3] = (bf16)v.w;
  out[i] = o;
}

// ------------------------- all 4 weights: W (K,N) fp32 -> W^T (N,K) bf16, z=which
__global__ void transpose_w4(const float* __restrict__ W0, const float* __restrict__ W1,
                             const float* __restrict__ W2, const float* __restrict__ W3,
                             bf16* __restrict__ T0, bf16* __restrict__ T3) {
  __shared__ float tile[32][33];
  const int z = blockIdx.z;
  const float* W = (z == 0) ? W0 : (z == 1) ? W1 : (z == 2) ? W2 : W3;
  bf16* WT = (z == 3) ? T3 : (T0 + (size_t)z * DIM * DIM);
  int tx = threadIdx.x, ty = threadIdx.y;
  int bx = blockIdx.x * 32, by = blockIdx.y * 32;
#pragma unroll
  for (int j = 0; j < 32; j += 8)
    tile[ty + j][tx] = W[(size_t)(by + ty + j) * DIM + bx + tx];
  __syncthreads();
#pragma unroll
  for (int j = 0; j < 32; j += 8)
    WT[(size_t)(bx + ty + j) * DIM + by + tx] = (bf16)tile[tx][ty + j];
}

// BK=64 GEMM LDS swizzle: row has 8 16B-chunks; slot (row,p) holds logical
// chunk p ^ (row&7). Quarter-wave b128 reads spread 2 lanes/bank-group (free).

// ----------------------------------------------------- fused QKV GEMM + RoPE
// A[4096,2048] bf16, BT = [WqT;WkT;WvT] (6144,2048) bf16.
// n0<2048: Q (rope, *QSC, row-major); <4096: K (rope, row-major);
// else: V written as V^T (B,NH,HD,SEQ).
__global__ __launch_bounds__(256) void gemm_qkv(const bf16* __restrict__ A,
                                                const bf16* __restrict__ BT,
                                                bf16* __restrict__ Qb,
                                                bf16* __restrict__ Kb,
                                                bf16* __restrict__ VTo) {
  __shared__ __attribute__((aligned(16))) bf16 As[128 * 64];
  __shared__ __attribute__((aligned(16))) bf16 Bs[128 * 64];
  const int tid = threadIdx.x;
  const int w = tid >> 6, lane = tid & 63;
  const int quad = lane >> 4, ln = lane & 15;
  const int m0 = blockIdx.y * 128, n0 = blockIdx.x * 128;
  const int wm = (w >> 1) * 64, wn = (w & 1) * 64;
  const int l7 = ln & 7;
  f32x4 acc[4][4] = {};

  for (int k0 = 0; k0 < DIM; k0 += 64) {
#pragma unroll
    for (int i = 0; i < 4; ++i) {
      const int c = i * 256 + tid;  // slot: row=c>>3, phys chunk p=c&7
      const int row = c >> 3, p = c & 7;
      LDS_ASYNC16(A  + (size_t)(m0 + row) * DIM + k0 + ((p ^ (row & 7)) * 8),
                  As + (size_t)(i * 256 + w * 64) * 8);
      LDS_ASYNC16(BT + (size_t)(n0 + row) * DIM + k0 + ((p ^ (row & 7)) * 8),
                  Bs + (size_t)(i * 256 + w * 64) * 8);
    }
    __syncthreads();
#pragma unroll
    for (int kh = 0; kh < 2; ++kh) {
      bf16x8 af[4], bfr[4];
#pragma unroll
      for (int t = 0; t < 4; ++t)
        af[t] = *(const bf16x8*)(As + (wm + t * 16 + ln) * 64 +
                                 (((kh * 4 + quad) ^ l7) * 8));
#pragma unroll
      for (int t = 0; t < 4; ++t)
        bfr[t] = *(const bf16x8*)(Bs + (wn + t * 16 + ln) * 64 +
                                  (((kh * 4 + quad) ^ l7) * 8));
#pragma unroll
      for (int mt = 0; mt < 4; ++mt)
#pragma unroll
        for (int nt = 0; nt < 4; ++nt)
          acc[mt][nt] = __builtin_amdgcn_mfma_f32_16x16x32_bf16(
              af[mt], bfr[nt], acc[mt][nt], 0, 0, 0);
    }
    __syncthreads();
  }

  const int sel = n0 >> 11;  // 0:Q 1:K 2:V  (block-uniform)
  if (sel == 2) {
#pragma unroll
    for (int mt = 0; mt < 4; ++mt)
#pragma unroll
      for (int nt = 0; nt < 4; ++nt) {
        int gr = m0 + wm + mt * 16 + quad * 4;
        int fc = (n0 + wn + nt * 16 + ln) & 2047;
        int b = gr >> 11, s0 = gr & (SEQ - 1);
        int h = fc >> 7, d = fc & (HD - 1);
        bf16x4 pk;
#pragma unroll
        for (int r = 0; r < 4; ++r) pk[r] = (bf16)acc[mt][nt][r];
        *(bf16x4*)(VTo + ((size_t)((b * NH + h) * HD + d)) * SEQ + s0) = pk;
      }
  } else {
    bf16* Dst = sel ? Kb : Qb;
    const float osc = sel ? 1.0f : QSC;
#pragma unroll
    for (int nt = 0; nt < 4; ++nt) {
      int gc = n0 + wn + nt * 16 + ln;
      int fc = gc & 2047, d = fc & (HD - 1);
      float freq = exp2f(-(float)(d >> 1) * FREQC);
      bool ev = !(d & 1);
#pragma unroll
      for (int mt = 0; mt < 4; ++mt) {
#pragma unroll
        for (int r = 0; r < 4; ++r) {
          int gr = m0 + wm + mt * 16 + quad * 4 + r;
          int s = gr & (SEQ - 1);
          float ang = (float)s * freq;
          float sn, cs;
          __sincosf(ang, &sn, &cs);
          float own = acc[mt][nt][r];
          float oth = __shfl_xor(own, 1);  // partner feature (d^1), lane ln^1
          float res = ev ? (own * cs - oth * sn) : (oth * sn + own * cs);
          Dst[(size_t)gr * DIM + fc] = (bf16)(res * osc);
        }
      }
    }
  }
}

// --------------------------------------------------------------------- GEMM
// C[M,N] = A * BT^T; MODE 2: C fp32 row-major (used for the Wo projection).
template <int MODE>
__global__ __launch_bounds__(256) void gemm_bt(const bf16* __restrict__ A,
                                               const bf16* __restrict__ BT,
                                               void* __restrict__ C) {
  __shared__ __attribute__((aligned(16))) bf16 As[128 * 64];
  __shared__ __attribute__((aligned(16))) bf16 Bs[128 * 64];
  const int tid = threadIdx.x;
  const int w = tid >> 6, lane = tid & 63;
  const int quad = lane >> 4, ln = lane & 15;
  const int m0 = blockIdx.y * 128, n0 = blockIdx.x * 128;
  const int wm = (w >> 1) * 64, wn = (w & 1) * 64;
  const int l7 = ln & 7;
  f32x4 acc[4][4] = {};

  for (int k0 = 0; k0 < DIM; k0 += 64) {
#pragma unroll
    for (int i = 0; i < 4; ++i) {
      const int c = i * 256 + tid;
      const int row = c >> 3, p = c & 7;
      LDS_ASYNC16(A  + (size_t)(m0 + row) * DIM + k0 + ((p ^ (row & 7)) * 8),
                  As + (size_t)(i * 256 + w * 64) * 8);
      LDS_ASYNC16(BT + (size_t)(n0 + row) * DIM + k0 + ((p ^ (row & 7)) * 8),
                  Bs + (size_t)(i * 256 + w * 64) * 8);
    }
    __syncthreads();
#pragma unroll
    for (int kh = 0; kh < 2; ++kh) {
      bf16x8 af[4], bfr[4];
#pragma unroll
      for (int t = 0; t < 4; ++t)
        af[t] = *(const bf16x8*)(As + (wm + t * 16 + ln) * 64 +
                                 (((kh * 4 + quad) ^ l7) * 8));
#pragma unroll
      for (int t = 0; t < 4; ++t)
        bfr[t] = *(const bf16x8*)(Bs + (wn + t * 16 + ln) * 64 +
                                  (((kh * 4 + quad) ^ l7) * 8));
#pragma unroll
      for (int mt = 0; mt < 4; ++mt)
#pragma unroll
        for (int nt = 0; nt < 4; ++nt)
          acc[mt][nt] = __builtin_amdgcn_mfma_f32_16x16x32_bf16(
              af[mt], bfr[nt], acc[mt][nt], 0, 0, 0);
    }
    __syncthreads();
  }

  if (MODE == 0) {
    bf16* Co = (bf16*)C;
#pragma unroll
    for (int mt = 0; mt < 4; ++mt)
#pragma unroll
      for (int nt = 0; nt < 4; ++nt) {
        int gr = m0 + wm + mt * 16 + quad * 4;
        int gc = n0 + wn + nt * 16 + ln;
#pragma unroll
        for (int r = 0; r < 4; ++r)
          Co[(size_t)(gr + r) * DIM + gc] = (bf16)acc[mt][nt][r];
      }
  } else {
    float* Co = (float*)C;
#pragma unroll
    for (int mt = 0; mt < 4; ++mt)
#pragma unroll
      for (int nt = 0; nt < 4; ++nt) {
        int gr = m0 + wm + mt * 16 + quad * 4;
        int gc = n0 + wn + nt * 16 + ln;
#pragma unroll
        for (int r = 0; r < 4; ++r)
          Co[(size_t)(gr + r) * DIM + gc] = acc[mt][nt][r];
      }
  }
}

// -------------------------- flash split-K chunk bookkeeping (chunk = 10 k-tiles)
// Per (b,h): t=0..4 direct (1 chunk); t=5..9: 2 chunks; t=10..14: 3; t=15: 4.
// 34 blocks/bh. Chunk 0 of a chunked tile writes unnormalized bf16 into O's
// final location; chunks >=1 go to Opart. All chunks write M/L.
__device__ __forceinline__ int ml_off(int t) {  // per-bh M/L slot base, stride 29
  return (t < 10) ? 2 * (t - 5) : (t < 15) ? 10 + 3 * (t - 10) : 25;
}
__device__ __forceinline__ int op_off(int t) {  // per-bh Opart slot base, stride 18
  return (t < 10) ? (t - 5) : (t < 15) ? 5 + 2 * (t - 10) : 15;
}

constexpr int PSTR = 72;
// 1-D grid, XCD-swizzled: lb = ((bh>>3)*34 + e)*8 + (bh&7), so lb%8 (the XCD
// on the 8-XCD round-robin) is constant per bh -> one bh's 1 MB of K/V stays
// in one XCD's L2 (4 bh x 1 MB per XCD) instead of being fetched by all 8.
__global__ __launch_bounds__(256) void flash_attn(
    const bf16* __restrict__ Q, const bf16* __restrict__ K,
    const bf16* __restrict__ VT, bf16* __restrict__ O,
    bf16* __restrict__ Opart, float* __restrict__ Mpart,
    float* __restrict__ Lpart) {
  __shared__ __attribute__((aligned(16))) bf16 Ks[64 * 128];
  __shared__ __attribute__((aligned(16))) bf16 VTs[128 * 64];
  __shared__ __attribute__((aligned(16))) bf16 Ps[4][32 * PSTR];
  const int tid = threadIdx.x;
  const int w = tid >> 6, lane = tid & 63, quad = lane >> 4, ln = lane & 15;
  const int lb = blockIdx.x;
  const int low3 = lb & 7, rest = lb >> 3;
  const int e = rest % 34;
  const int bh = (rest / 34) * 8 + low3;
  int t, c0, nc;
  if (e < 5)       { t = e;                  c0 = 0;               nc = 1; }
  else if (e < 15) { t = 5 + ((e - 5) >> 1); c0 = (e - 5) & 1;     nc = 2; }
  else if (e < 30) { int q = (e - 15) / 3;   t = 10 + q; c0 = (e - 15) - 3 * q; nc = 3; }
  else             { t = 15;                 c0 = e - 30;          nc = 4; }
  const int q0 = t * 128;
  const int ktN = 2 * (t + 1);
  const int kt0 = c0 * 10;
  const int kt1 = min(kt0 + 10, ktN);
  const bool chunked = (nc > 1);
  const int b = bh >> 4, h = bh & 15;

  bf16x8 qf[2][4];
#pragma unroll
  for (int mt = 0; mt < 2; ++mt)
#pragma unroll
    for (int kc = 0; kc < 4; ++kc)
      qf[mt][kc] = *(const bf16x8*)(Q + ((size_t)b * SEQ + q0 + w * 32 + mt * 16 + ln) * DIM +
                                    h * HD + kc * 32 + quad * 8);
  f32x4 o[2][8] = {};
  float mst[2][4], lst[2][4];
#pragma unroll
  for (int mt = 0; mt < 2; ++mt)
#pragma unroll
    for (int r = 0; r < 4; ++r) { mst[mt][r] = -1e30f; lst[mt][r] = 0.f; }

  for (int kt = kt0; kt < kt1; ++kt) {
    __syncthreads();
#pragma unroll
    for (int i = 0; i < 4; ++i) {
      const int c = i * 256 + tid;
      LDS_ASYNC16(K + ((size_t)b * SEQ + kt * 64 + (c >> 4)) * DIM + h * HD +
                      (((c & 15) ^ ((c >> 4) & 15)) * 8),
                  Ks + (size_t)(i * 256 + w * 64) * 8);
      LDS_ASYNC16(VT + ((size_t)((b * NH + h) * HD) + (c >> 3)) * SEQ + kt * 64 +
                      (((c & 7) ^ ((c >> 3) & 7)) * 8),
                  VTs + (size_t)(i * 256 + w * 64) * 8);
    }
    __syncthreads();

    // S = Q K^T (exp2 domain; scale pre-folded into Q)
    f32x4 s[2][4] = {};
#pragma unroll
    for (int nt = 0; nt < 4; ++nt) {
      bf16x8 kf[4];
#pragma unroll
      for (int kc = 0; kc < 4; ++kc)
        kf[kc] = *(const bf16x8*)(Ks + (nt * 16 + ln) * 128 +
                                  (((kc * 4 + quad) ^ ln) * 8));
#pragma unroll
      for (int kc = 0; kc < 4; ++kc)
#pragma unroll
        for (int mt = 0; mt < 2; ++mt)
          s[mt][nt] = __builtin_amdgcn_mfma_f32_16x16x32_bf16(
              qf[mt][kc], kf[kc], s[mt][nt], 0, 0, 0);
    }

    const bool diag = (kt * 64 + 63 > q0);
    if (diag) {
#pragma unroll
      for (int mt = 0; mt < 2; ++mt)
#pragma unroll
        for (int nt = 0; nt < 4; ++nt)
#pragma unroll
          for (int r = 0; r < 4; ++r) {
            int kg = kt * 64 + nt * 16 + ln;
            int qg = q0 + w * 32 + mt * 16 + quad * 4 + r;
            if (kg > qg) s[mt][nt][r] = -1e30f;
          }
    }

    // online softmax, exp2 domain; DPP 16-lane max (no LDS shuffles)
#pragma unroll
    for (int mt = 0; mt < 2; ++mt)
#pragma unroll
      for (int r = 0; r < 4; ++r) {
        float rm = fmaxf(fmaxf(s[mt][0][r], s[mt][1][r]),
                         fmaxf(s[mt][2][r], s[mt][3][r]));
        rm = rowmax16(rm);
        float mold = mst[mt][r];
        float mnew = fmaxf(mold, rm);
        float alpha = exp2f(mold - mnew);
        mst[mt][r] = mnew;
        float rs = 0.f;
#pragma unroll
        for (int nt = 0; nt < 4; ++nt) {
          float p = exp2f(s[mt][nt][r] - mnew);
          rs += p;
          Ps[w][(mt * 16 + quad * 4 + r) * PSTR + nt * 16 + ln] = (bf16)p;
        }
        lst[mt][r] = lst[mt][r] * alpha + rs;
#pragma unroll
        for (int nd = 0; nd < 8; ++nd) o[mt][nd][r] *= alpha;
      }
    __syncthreads();

    // O += P V
#pragma unroll
    for (int kc2 = 0; kc2 < 2; ++kc2) {
      bf16x8 pf[2];
#pragma unroll
      for (int mt = 0; mt < 2; ++mt)
        pf[mt] = *(const bf16x8*)(&Ps[w][(mt * 16 + ln) * PSTR + kc2 * 32 + quad * 8]);
#pragma unroll
      for (int nd = 0; nd < 8; ++nd) {
        bf16x8 vf = *(const bf16x8*)(VTs + (nd * 16 + ln) * 64 +
                                     (((kc2 * 4 + quad) ^ (ln & 7)) * 8));
#pragma unroll
        for (int mt = 0; mt < 2; ++mt)
          o[mt][nd] = __builtin_amdgcn_mfma_f32_16x16x32_bf16(
              pf[mt], vf, o[mt][nd], 0, 0, 0);
      }
    }
  }

  if (!chunked) {
#pragma unroll
    for (int mt = 0; mt < 2; ++mt)
#pragma unroll
      for (int r = 0; r < 4; ++r) {
        float inv = 1.f / rowsum16(lst[mt][r]);
        int qg = q0 + w * 32 + mt * 16 + quad * 4 + r;
#pragma unroll
        for (int nd = 0; nd < 8; ++nd)
          O[((size_t)b * SEQ + qg) * DIM + h * HD + nd * 16 + ln] =
              (bf16)(o[mt][nd][r] * inv);
      }
  } else {
    const int mls = bh * 29 + ml_off(t) + c0;
    bf16* Op = (c0 == 0) ? nullptr
                         : Opart + (size_t)(bh * 18 + op_off(t) + (c0 - 1)) * (128 * 128);
#pragma unroll
    for (int mt = 0; mt < 2; ++mt)
#pragma unroll
      for (int r = 0; r < 4; ++r) {
        float l = rowsum16(lst[mt][r]);
        int qr = w * 32 + mt * 16 + quad * 4 + r;
        if (ln == 0) {
          Mpart[mls * 128 + qr] = mst[mt][r];
          Lpart[mls * 128 + qr] = l;
        }
        if (c0 == 0) {
#pragma unroll
          for (int nd = 0; nd < 8; ++nd)
            O[((size_t)b * SEQ + q0 + qr) * DIM + h * HD + nd * 16 + ln] =
                (bf16)o[mt][nd][r];
        } else {
#pragma unroll
          for (int nd = 0; nd < 8; ++nd)
            Op[qr * 128 + nd * 16 + ln] = (bf16)o[mt][nd][r];
        }
      }
  }
}

// ----------------------------------------------------- merge split-K partials
// grid (32, 11): bh x (t-5). Chunk 0 lives unnormalized in O; chunks 1..nc-1
// in Opart. Combine with max-rebased weights, normalize, write O.
__global__ __launch_bounds__(256) void flash_merge(const bf16* __restrict__ Opart,
                                                   const float* __restrict__ Mpart,
                                                   const float* __restrict__ Lpart,
                                                   bf16* __restrict__ O) {
  const int bh = blockIdx.x;
  const int t = 5 + blockIdx.y;
  const int nc = (t < 10) ? 2 : (t < 15) ? 3 : 4;
  const int b = bh >> 4, h = bh & 15;
  const int row = threadIdx.x >> 1, half = threadIdx.x & 1;
  const int mlb = bh * 29 + ml_off(t);
  float m[4], l[4], wt[4];
  float M = -1e30f;
  for (int c = 0; c < nc; ++c) {
    m[c] = Mpart[(mlb + c) * 128 + row];
    l[c] = Lpart[(mlb + c) * 128 + row];
    M = fmaxf(M, m[c]);
  }
  float wsum = 0.f;
  for (int c = 0; c < nc; ++c) { wt[c] = exp2f(m[c] - M); wsum += wt[c] * l[c]; }
  const float inv = 1.f / wsum;
  bf16* dst = O + ((size_t)b * SEQ + t * 128 + row) * DIM + h * HD + half * 64;
  const bf16* pb = Opart + (size_t)(bh * 18 + op_off(t)) * (128 * 128) + row * 128 + half * 64;
#pragma unroll
  for (int j = 0; j < 8; ++j) {
    bf16x8 a0 = *(const bf16x8*)(dst + j * 8);
    float acc[8];
#pragma unroll
    for (int k = 0; k < 8; ++k) acc[k] = wt[0] * (float)a0[k];
    for (int c = 1; c < nc; ++c) {
      bf16x8 a = *(const bf16x8*)(pb + (size_t)(c - 1) * (128 * 128) + j * 8);
#pragma unroll
      for (int k = 0; k < 8; ++k) acc[k] += wt[c] * (float)a[k];
    }
    bf16x8 o8;
#pragma unroll
    for (int k = 0; k < 8; ++k) o8[k] = (bf16)(acc[k] * inv);
    *(bf16x8*)(dst + j * 8) = o8;
  }
}

// ------------------------------------------------------------------- launch
extern "C" void kernel_launch(void* const* d_in, const int* in_sizes, int n_in,
                              void* d_out, int out_size, void* d_ws, size_t ws_size,
                              hipStream_t stream) {
  (void)in_sizes; (void)n_in; (void)out_size; (void)ws_size;
  const float* x  = (const float*)d_in[0];
  const float* Wq = (const float*)d_in[1];
  const float* Wk = (const float*)d_in[2];
  const float* Wv = (const float*)d_in[3];
  const float* Wo = (const float*)d_in[4];

  char* ws = (char*)d_ws;
  const size_t MB = 1u << 20;
  const size_t WB = (size_t)DIM * DIM * 2;  // 8 MB
  bf16* WTqkv = (bf16*)(ws);                // 24 MB; dead after gemm_qkv
  bf16* WoT   = (bf16*)(ws + 3 * WB);       // 8 MB
  bf16* xb    = (bf16*)(ws + 32 * MB);      // 16 MB; Ab aliases after QKV
  bf16* Qb    = (bf16*)(ws + 48 * MB);
  bf16* Kb    = (bf16*)(ws + 64 * MB);
  bf16* VT    = (bf16*)(ws + 80 * MB);
  bf16* Ab    = xb;
  // split-K partials alias the (dead) WTqkv region:
  // Opart 18.9 MB (32 bh x 18 slots x 32 KB) + M/L ~0.5 MB each
  bf16*  Opart = (bf16*)(ws);
  float* Mpart = (float*)(ws + 19 * MB);
  float* Lpart = (float*)(ws + 19 * MB + 512 * 1024);

  int n4 = BATCH * SEQ * DIM / 4;
  cvt_f32_to_bf16<<<n4 / 256, 256, 0, stream>>>((const float4*)x, (bf16x4*)xb, n4);
  dim3 tb(32, 8), tg(DIM / 32, DIM / 32, 4);
  transpose_w4<<<tg, tb, 0, stream>>>(Wq, Wk, Wv, Wo, WTqkv, WoT);

  dim3 qg(3 * DIM / 128, BATCH * SEQ / 128);  // 48 x 32
  gemm_qkv<<<qg, 256, 0, stream>>>(xb, WTqkv, Qb, Kb, VT);

  // 1-D XCD-swizzled flash grid: 34 chunks x 32 bh
  flash_attn<<<34 * BATCH * NH, 256, 0, stream>>>(Qb, Kb, VT, Ab, Opart, Mpart, Lpart);
  dim3 mg(BATCH * NH, 11);
  flash_merge<<<mg, 256, 0, stream>>>(Opart, Mpart, Lpart, Ab);

  dim3 gg(DIM / 128, BATCH * SEQ / 128);
  gemm_bt<2><<<gg, 256, 0, stream>>>(Ab, WoT, d_out);
}